// Round 10
// baseline (5117.554 us; speedup 1.0000x reference)
//
#include <hip/hip_runtime.h>
#include <hip/hip_bf16.h>

typedef unsigned short ushort_t;
typedef __bf16 bf16x8 __attribute__((ext_vector_type(8)));
typedef float f32x4 __attribute__((ext_vector_type(4)));

__device__ __forceinline__ void gload_lds16(const void* g, void* l) {
    __builtin_amdgcn_global_load_lds(
        (const __attribute__((address_space(1))) void*)g,
        (__attribute__((address_space(3))) void*)l, 16, 0, 0);
}

__device__ __forceinline__ float elu1(float v) { return v > 0.f ? v : expm1f(v); }

// stage [256 rows][32 k] bf16 (16 KiB): 2 loads/thread (512 thr). LDS dest
// linear (t*16B), global source pre-swizzled: chunk bit1 ^= row bit3.
__device__ __forceinline__ void stage_half256(const ushort_t* g, int ldg,
                                              ushort_t* lds, int t) {
    const int row = t >> 2;
    const int chunk = (t & 3) ^ ((t >> 4) & 2);
    const ushort_t* src = g + (size_t)row * ldg + chunk * 8;
    const int wo = (t >> 6) * 512;
    gload_lds16(src, lds + wo);
    gload_lds16(src + (size_t)128 * ldg, lds + 4096 + wo);
}
// stage [128 rows][32 k] (8 KiB): 1 load/thread
__device__ __forceinline__ void stage_half128(const ushort_t* g, int ldg,
                                              ushort_t* lds, int t) {
    const int row = t >> 2;
    const int chunk = (t & 3) ^ ((t >> 4) & 2);
    gload_lds16(g + (size_t)row * ldg + chunk * 8, lds + (t >> 6) * 512);
}

// ---------------------------------------------------------------------------
// 128x256 MFMA GEMM, BK=32, 8 waves (2M x 4N), 64x64/wave (acc[4][4]).
// R9 mechanics, 2-deep LDS double-buffer (48 KiB) -> 3 blocks/CU (24 waves).
// ONE barrier/kt; stage kt+1 during kt; vmcnt(0) drain at kt end (gap ~1 body
// >> HBM latency). Static buffer offsets via unroll-by-2.
// LDS layout (ushorts): A bufs @ 0,4096 ; B bufs @ 8192,16384.
// ---------------------------------------------------------------------------
#define LDA(J_, MI_) (*(const bf16x8*)(LDSc + vA + ((J_) * 8192 + (MI_) * 1024)))
#define LDB(J_, NI_) (*(const bf16x8*)(LDSc + vB + ((J_) * 16384 + (NI_) * 1024)))

#define GBODY(J_)                                                              \
  {                                                                            \
    bf16x8 a0 = LDA(J_, 0), a1 = LDA(J_, 1), a2 = LDA(J_, 2), a3 = LDA(J_, 3); \
    bf16x8 b0 = LDB(J_, 0), b1 = LDB(J_, 1), b2 = LDB(J_, 2), b3 = LDB(J_, 3); \
    if (kt + 1 < NT) {                                                         \
      stage_half256(Btile + (size_t)(kt + 1) * 32, K, &LDS[8192 + ((J_) ^ 1) * 8192], t); \
      stage_half128(Atile + (size_t)(kt + 1) * 32, lda, &LDS[((J_) ^ 1) * 4096], t); \
    }                                                                          \
    __builtin_amdgcn_s_setprio(1);                                             \
    acc[0][0] = __builtin_amdgcn_mfma_f32_16x16x32_bf16(a0, b0, acc[0][0], 0, 0, 0); \
    acc[0][1] = __builtin_amdgcn_mfma_f32_16x16x32_bf16(a0, b1, acc[0][1], 0, 0, 0); \
    acc[0][2] = __builtin_amdgcn_mfma_f32_16x16x32_bf16(a0, b2, acc[0][2], 0, 0, 0); \
    acc[0][3] = __builtin_amdgcn_mfma_f32_16x16x32_bf16(a0, b3, acc[0][3], 0, 0, 0); \
    acc[1][0] = __builtin_amdgcn_mfma_f32_16x16x32_bf16(a1, b0, acc[1][0], 0, 0, 0); \
    acc[1][1] = __builtin_amdgcn_mfma_f32_16x16x32_bf16(a1, b1, acc[1][1], 0, 0, 0); \
    acc[1][2] = __builtin_amdgcn_mfma_f32_16x16x32_bf16(a1, b2, acc[1][2], 0, 0, 0); \
    acc[1][3] = __builtin_amdgcn_mfma_f32_16x16x32_bf16(a1, b3, acc[1][3], 0, 0, 0); \
    acc[2][0] = __builtin_amdgcn_mfma_f32_16x16x32_bf16(a2, b0, acc[2][0], 0, 0, 0); \
    acc[2][1] = __builtin_amdgcn_mfma_f32_16x16x32_bf16(a2, b1, acc[2][1], 0, 0, 0); \
    acc[2][2] = __builtin_amdgcn_mfma_f32_16x16x32_bf16(a2, b2, acc[2][2], 0, 0, 0); \
    acc[2][3] = __builtin_amdgcn_mfma_f32_16x16x32_bf16(a2, b3, acc[2][3], 0, 0, 0); \
    acc[3][0] = __builtin_amdgcn_mfma_f32_16x16x32_bf16(a3, b0, acc[3][0], 0, 0, 0); \
    acc[3][1] = __builtin_amdgcn_mfma_f32_16x16x32_bf16(a3, b1, acc[3][1], 0, 0, 0); \
    acc[3][2] = __builtin_amdgcn_mfma_f32_16x16x32_bf16(a3, b2, acc[3][2], 0, 0, 0); \
    acc[3][3] = __builtin_amdgcn_mfma_f32_16x16x32_bf16(a3, b3, acc[3][3], 0, 0, 0); \
    __builtin_amdgcn_s_setprio(0);                                             \
    asm volatile("s_waitcnt vmcnt(0)" ::: "memory");                           \
    __builtin_amdgcn_s_barrier();                                              \
    asm volatile("" ::: "memory");                                             \
    ++kt;                                                                      \
  }

template<int MODE, int NT, int LNB>
__global__ __launch_bounds__(512, 6) void gemmS(
    const __hip_bfloat16* __restrict__ A, size_t sAc, int lda,
    const __hip_bfloat16* __restrict__ Wt, size_t sWc,
    const float* __restrict__ bias, int sBc,
    __hip_bfloat16* __restrict__ Obf, size_t sOc, int ldo)
{
    constexpr int K = NT * 32;
    __shared__ __align__(16) ushort_t LDS[24576];   // 48 KiB

    const int t = threadIdx.x;
    const int wid = t >> 6, lane = t & 63;
    const int wm = wid >> 2, wn = wid & 3;
    const int fl = lane & 15, fh = lane >> 4;

    // bijective XCD swizzle: orig%8 -> XCD gets a contiguous chunk (= 1 chart).
    // bn in LOW bits of inner: co-resident blocks share the 2 MB B-slab (L2)
    // and read each A-row-block once (4 bn siblings launch together).
    const int orig = blockIdx.x + 32 * blockIdx.y + (32 << LNB) * blockIdx.z;
    const int q = (32 << LNB);                 // nwg/8 (gridDim.z == 8)
    const int wg = (orig & 7) * q + (orig >> 3);
    const int z = wg >> (5 + LNB);
    const int inner = wg & ((32 << LNB) - 1);
    const int bm = (inner >> LNB) * 128;
    const int bn = (inner & ((1 << LNB) - 1)) * 256;

    const ushort_t* Atile = (const ushort_t*)A + (size_t)z * sAc + (size_t)bm * lda;
    const ushort_t* Btile = (const ushort_t*)Wt + (size_t)z * sWc + (size_t)bn * K;

    // per-lane LDS read addresses; swizzle reduced to lane-only form:
    // (r>>2)&2 == (fl>>2)&2 for r = 64*w + 16*frag + fl (frag-independent).
    const char* LDSc = (const char*)&LDS[0];
    const unsigned lanepart = fl * 64 + ((fh ^ ((fl >> 2) & 2)) << 4);
    const unsigned vA = wm * 4096 + lanepart;
    const unsigned vB = 16384 + wn * 4096 + lanepart;

    f32x4 acc[4][4];
    #pragma unroll
    for (int i = 0; i < 4; ++i)
        #pragma unroll
        for (int j = 0; j < 4; ++j) acc[i][j] = (f32x4){0.f, 0.f, 0.f, 0.f};

    // prologue: stage kt0 -> buf0 (3 loads); drain
    stage_half256(Btile, K, &LDS[8192], t);
    stage_half128(Atile, lda, &LDS[0], t);
    asm volatile("s_waitcnt vmcnt(0)" ::: "memory");
    __builtin_amdgcn_s_barrier();
    asm volatile("" ::: "memory");

    int kt = 0;
    while (kt < NT) { GBODY(0) GBODY(1) }   // NT even (16 or 32)

    // epilogue: C/D layout col=lane&15, row=(lane>>4)*4+reg
    #pragma unroll
    for (int mi = 0; mi < 4; ++mi) {
        #pragma unroll
        for (int ni = 0; ni < 4; ++ni) {
            const int n = bn + wn * 64 + ni * 16 + fl;
            const float bv = bias[z * sBc + n];
            #pragma unroll
            for (int r = 0; r < 4; ++r) {
                const int m = bm + wm * 64 + mi * 16 + fh * 4 + r;
                float v = acc[mi][ni][r] + bv;
                if (MODE == 0) v = elu1(v);
                Obf[(size_t)z * sOc + (size_t)m * ldo + n] = __float2bfloat16(v);
            }
        }
    }
}

// ---------------------------------------------------------------------------
// 2-phase 128xBN kernel (round-2, proven) — for enc4 (N=64) / dec1 (K=64)
// ---------------------------------------------------------------------------
template<int BN, int MODE>
__global__ __launch_bounds__(256) void mfma_gemm(
    const __hip_bfloat16* __restrict__ A, size_t sAc, int lda, int K,
    const __hip_bfloat16* __restrict__ Wt, size_t sWc,
    const float* __restrict__ bias, int sBc,
    __hip_bfloat16* __restrict__ Obf, size_t sOc, int ldo,
    float* __restrict__ Of, int c0)
{
    constexpr int NI = BN / 32;
    __shared__ __align__(16) ushort_t As2[128 * 32];
    __shared__ __align__(16) ushort_t Bs2[BN * 32];

    const int t = threadIdx.x;
    const int wid = t >> 6, lane = t & 63;
    const int wm = wid >> 1, wn = wid & 1;
    const int z = blockIdx.z;
    const int bm = blockIdx.x * 128;
    const int bn = blockIdx.y * BN;

    const ushort_t* Ap = (const ushort_t*)A + (size_t)z * sAc;
    const ushort_t* Wp = (const ushort_t*)Wt + (size_t)z * sWc;

    const int srow = t >> 2;
    const int scol = (t & 3) << 3;
    const int fl = lane & 15, fh = lane >> 4;

    f32x4 zero4 = {0.f, 0.f, 0.f, 0.f};
    f32x4 acc[4][NI];
    #pragma unroll
    for (int mi = 0; mi < 4; ++mi)
        #pragma unroll
        for (int ni = 0; ni < NI; ++ni) acc[mi][ni] = zero4;

    for (int k0 = 0; k0 < K; k0 += 32) {
        #pragma unroll
        for (int i = 0; i < 2; ++i)
            gload_lds16(Ap + (size_t)(bm + i * 64 + srow) * lda + k0 + scol,
                        &As2[i * 2048 + wid * 512]);
        #pragma unroll
        for (int i = 0; i < BN / 64; ++i)
            gload_lds16(Wp + (size_t)(bn + i * 64 + srow) * K + k0 + scol,
                        &Bs2[i * 2048 + wid * 512]);
        __syncthreads();

        bf16x8 af[4], bfr[NI];
        #pragma unroll
        for (int mi = 0; mi < 4; ++mi)
            af[mi] = *(const bf16x8*)&As2[(wm * 64 + mi * 16 + fl) * 32 + fh * 8];
        #pragma unroll
        for (int ni = 0; ni < NI; ++ni)
            bfr[ni] = *(const bf16x8*)&Bs2[(wn * (BN / 2) + ni * 16 + fl) * 32 + fh * 8];
        #pragma unroll
        for (int mi = 0; mi < 4; ++mi)
            #pragma unroll
            for (int ni = 0; ni < NI; ++ni)
                acc[mi][ni] = __builtin_amdgcn_mfma_f32_16x16x32_bf16(
                    af[mi], bfr[ni], acc[mi][ni], 0, 0, 0);
        __syncthreads();
    }

    #pragma unroll
    for (int mi = 0; mi < 4; ++mi) {
        #pragma unroll
        for (int ni = 0; ni < NI; ++ni) {
            const int n = bn + wn * (BN / 2) + ni * 16 + fl;
            const float bv = bias[z * sBc + n];
            #pragma unroll
            for (int r = 0; r < 4; ++r) {
                const int m = bm + wm * 64 + mi * 16 + fh * 4 + r;
                float v = acc[mi][ni][r] + bv;
                if (MODE == 0) v = elu1(v);
                Obf[(size_t)z * sOc + (size_t)m * ldo + n] = __float2bfloat16(v);
                if (MODE == 1)
                    Of[(size_t)m * 512 + (size_t)(c0 + z) * 64 + n] = v;
            }
        }
    }
}

// fp32 [K][N] -> bf16 [N][K] (transpose + convert)
__global__ __launch_bounds__(256) void cvtT(
    const float* __restrict__ in, __hip_bfloat16* __restrict__ out,
    int K, int N, size_t sInC, size_t sOutC)
{
    __shared__ float tile[32][33];
    const float* ip = in + blockIdx.z * sInC;
    __hip_bfloat16* op = out + blockIdx.z * sOutC;
    const int n0 = blockIdx.x * 32, k0 = blockIdx.y * 32;
    const int x = threadIdx.x, y = threadIdx.y;
    #pragma unroll
    for (int j = 0; j < 4; ++j)
        tile[y + 8 * j][x] = ip[(size_t)(k0 + y + 8 * j) * N + n0 + x];
    __syncthreads();
    #pragma unroll
    for (int j = 0; j < 4; ++j)
        op[(size_t)(n0 + y + 8 * j) * K + k0 + x] = __float2bfloat16(tile[x][y + 8 * j]);
}

__global__ __launch_bounds__(256) void cvtx(
    const float* __restrict__ in, __hip_bfloat16* __restrict__ out, int n4)
{
    int i = blockIdx.x * 256 + threadIdx.x;
    if (i < n4) {
        float4 v = ((const float4*)in)[i];
        out[i * 4 + 0] = __float2bfloat16(v.x);
        out[i * 4 + 1] = __float2bfloat16(v.y);
        out[i * 4 + 2] = __float2bfloat16(v.z);
        out[i * 4 + 3] = __float2bfloat16(v.w);
    }
}

__global__ __launch_bounds__(256) void recon_group(
    const float* __restrict__ x, const __hip_bfloat16* __restrict__ xrec,
    const float* __restrict__ p, float* __restrict__ recon_x,
    float* __restrict__ err, int c0, int G)
{
    const int wid = threadIdx.x >> 6, lane = threadIdx.x & 63;
    const size_t b = (size_t)blockIdx.x * 4 + wid;
    const float4* xp = (const float4*)(x + b * 512);
    const float4 x0 = xp[lane * 2], x1 = xp[lane * 2 + 1];
    const float xv[8] = {x0.x, x0.y, x0.z, x0.w, x1.x, x1.y, x1.z, x1.w};
    float r[8] = {0.f, 0.f, 0.f, 0.f, 0.f, 0.f, 0.f, 0.f};

    for (int cc = 0; cc < G; ++cc) {
        const ushort_t* xr =
            (const ushort_t*)xrec + ((size_t)cc * 4096 + b) * 512 + lane * 8;
        bf16x8 v = *(const bf16x8*)xr;
        float pv = p[b * 8 + c0 + cc];
        float e = 0.f;
        #pragma unroll
        for (int j = 0; j < 8; ++j) {
            float f = (float)v[j];
            r[j] = fmaf(pv, f, r[j]);
            float d = xv[j] - f;
            e = fmaf(d, d, e);
        }
        #pragma unroll
        for (int off = 1; off < 64; off <<= 1) e += __shfl_xor(e, off, 64);
        if (lane == 0) err[b * 8 + c0 + cc] = e;
    }

    float4* op = (float4*)(recon_x + b * 512);
    float4 o0 = {r[0], r[1], r[2], r[3]}, o1 = {r[4], r[5], r[6], r[7]};
    if (c0) {
        float4 t0 = op[lane * 2], t1 = op[lane * 2 + 1];
        o0.x += t0.x; o0.y += t0.y; o0.z += t0.z; o0.w += t0.w;
        o1.x += t1.x; o1.y += t1.y; o1.z += t1.z; o1.w += t1.w;
    }
    op[lane * 2] = o0;
    op[lane * 2 + 1] = o1;
}

__global__ __launch_bounds__(256) void proj_sparsemax(
    const float* __restrict__ x, const float* __restrict__ Wp,
    const float* __restrict__ bp, float* __restrict__ p, int B, int D)
{
    int gw = (blockIdx.x * blockDim.x + threadIdx.x) >> 6;
    int lane = threadIdx.x & 63;
    if (gw >= B) return;
    const float* xr = x + (size_t)gw * D;
    float acc[8] = {0.f, 0.f, 0.f, 0.f, 0.f, 0.f, 0.f, 0.f};
    for (int d = lane; d < D; d += 64) {
        float xv = xr[d];
        #pragma unroll
        for (int c = 0; c < 8; ++c) acc[c] = fmaf(xv, Wp[d * 8 + c], acc[c]);
    }
    #pragma unroll
    for (int off = 32; off > 0; off >>= 1) {
        #pragma unroll
        for (int c = 0; c < 8; ++c) acc[c] += __shfl_xor(acc[c], off, 64);
    }
    if (lane == 0) {
        float s[8], zs[8];
        #pragma unroll
        for (int c = 0; c < 8; ++c) { s[c] = acc[c] + bp[c]; zs[c] = s[c]; }
        for (int i = 1; i < 8; ++i) {
            float v = zs[i];
            int j = i - 1;
            while (j >= 0 && zs[j] < v) { zs[j + 1] = zs[j]; --j; }
            zs[j + 1] = v;
        }
        float cs = 0.f, csel = 1.f;
        int kz = 1;
        for (int k = 1; k <= 8; ++k) {
            cs += zs[k - 1];
            if (1.f + (float)k * zs[k - 1] > cs) { kz = k; csel = cs; }
        }
        float tau = (csel - 1.f) / (float)kz;
        #pragma unroll
        for (int c = 0; c < 8; ++c) p[gw * 8 + c] = fmaxf(s[c] - tau, 0.f);
    }
}

__global__ __launch_bounds__(256) void losses_rows(
    const float* __restrict__ p, const float* __restrict__ err,
    float* __restrict__ acc, int B)
{
    __shared__ float s[10];
    int t = threadIdx.x;
    if (t < 10) s[t] = 0.f;
    __syncthreads();
    int b = blockIdx.x * 256 + t;
    if (b < B) {
        float pr[8], er[8];
        #pragma unroll
        for (int c = 0; c < 8; ++c) { pr[c] = p[b * 8 + c]; er[c] = err[b * 8 + c]; }
        float mn = er[0];
        #pragma unroll
        for (int c = 1; c < 8; ++c) mn = fminf(mn, er[c]);
        float q[8], se = 0.f;
        #pragma unroll
        for (int c = 0; c < 8; ++c) { q[c] = expf(mn - er[c]); se += q[c]; }
        float rl = 0.f, tl = 0.f;
        #pragma unroll
        for (int c = 0; c < 8; ++c) {
            rl = fmaf(pr[c], er[c], rl);
            tl = fmaf(q[c] / se, logf(pr[c] + 1e-8f), tl);
        }
        atomicAdd(&s[0], rl);
        atomicAdd(&s[1], tl);
        #pragma unroll
        for (int c = 0; c < 8; ++c) atomicAdd(&s[2 + c], pr[c]);
    }
    __syncthreads();
    if (t < 10) atomicAdd(&acc[t], s[t]);
}

__global__ __launch_bounds__(256) void mse_reduce(
    const float* __restrict__ recon_x, const float* __restrict__ x,
    float* __restrict__ acc, int n)
{
    float sm = 0.f;
    for (int i = blockIdx.x * 256 + threadIdx.x; i < n; i += gridDim.x * 256) {
        float d = recon_x[i] - x[i];
        sm = fmaf(d, d, sm);
    }
    __shared__ float sh;
    if (threadIdx.x == 0) sh = 0.f;
    __syncthreads();
    atomicAdd(&sh, sm);
    __syncthreads();
    if (threadIdx.x == 0) atomicAdd(&acc[10], sh);
}

__global__ void finalize_kernel(const float* __restrict__ acc,
                                float* __restrict__ scal, int B, int D)
{
    float invB = 1.f / (float)B;
    float recon = acc[0] * invB;
    float trans = -acc[1] * invB;
    float nondom = 0.f;
    for (int c = 0; c < 8; ++c) {
        float mp = acc[2 + c] * invB;
        float d = mp - 0.125f;
        nondom = fmaf(d, d, nondom);
    }
    float mse = acc[10] / ((float)B * (float)D);
    scal[0] = recon + trans + nondom;
    scal[1] = recon;
    scal[2] = nondom;
    scal[3] = trans;
    scal[4] = mse;
}

extern "C" void kernel_launch(void* const* d_in, const int* in_sizes, int n_in,
                              void* d_out, int out_size, void* d_ws, size_t ws_size,
                              hipStream_t stream)
{
    const int B = 4096, D = 512, L = 64, H = 1024, C = 8;

    const float* x   = (const float*)d_in[0];
    const float* We1 = (const float*)d_in[1];
    const float* be1 = (const float*)d_in[2];
    const float* We2 = (const float*)d_in[3];
    const float* be2 = (const float*)d_in[4];
    const float* We3 = (const float*)d_in[5];
    const float* be3 = (const float*)d_in[6];
    const float* We4 = (const float*)d_in[7];
    const float* be4 = (const float*)d_in[8];
    const float* Wd1 = (const float*)d_in[9];
    const float* bd1 = (const float*)d_in[10];
    const float* Wd2 = (const float*)d_in[11];
    const float* bd2 = (const float*)d_in[12];
    const float* Wd3 = (const float*)d_in[13];
    const float* bd3 = (const float*)d_in[14];
    const float* Wd4 = (const float*)d_in[15];
    const float* bd4 = (const float*)d_in[16];
    const float* Wp  = (const float*)d_in[17];
    const float* bp  = (const float*)d_in[18];

    float* out     = (float*)d_out;
    float* recon_x = out;                          // [B,D]
    float* zfp     = out + (size_t)B * D;          // [B,C,L]
    float* p       = zfp + (size_t)B * C * L;      // [B,C]
    float* scal    = p + (size_t)B * C;            // 5 scalars

    const size_t perG = ((size_t)H * H + 2ull * B * H + (size_t)B * D) * 2ull;
    const size_t fixedB = ((size_t)B * D + (size_t)C * B * L) * 2ull +
                          ((size_t)B * C + 16) * 4ull + 1024;
    int G = 8;
    while (G > 1 && fixedB + perG * (size_t)G > ws_size) G >>= 1;

    char* w = (char*)d_ws;
    __hip_bfloat16* xbf  = (__hip_bfloat16*)w; w += (size_t)B * D * 2;
    __hip_bfloat16* zbf  = (__hip_bfloat16*)w; w += (size_t)C * B * L * 2;
    __hip_bfloat16* wbuf = (__hip_bfloat16*)w; w += (size_t)G * H * H * 2;
    __hip_bfloat16* hA   = (__hip_bfloat16*)w; w += (size_t)G * B * H * 2;
    __hip_bfloat16* hB   = (__hip_bfloat16*)w; w += (size_t)G * B * H * 2;
    __hip_bfloat16* xrec = (__hip_bfloat16*)w; w += (size_t)G * B * D * 2;
    float* err = (float*)w; w += (size_t)B * C * 4;
    float* acc = (float*)w;

    hipMemsetAsync(acc, 0, 16 * sizeof(float), stream);

    cvtx<<<(B * D / 4 + 255) / 256, 256, 0, stream>>>(x, xbf, B * D / 4);
    proj_sparsemax<<<B / 4, 256, 0, stream>>>(x, Wp, bp, p, B, D);

    const dim3 cb(32, 8);
    const dim3 gSH(32, 4, 8);   // 128x256 tiles, N=1024
    const dim3 gSD(32, 2, 8);   // N=512

    for (int c0 = 0; c0 < C; c0 += G) {
        // enc1: [B,512] x [512,1024] -> hA (ELU), K=512 -> NT=16
        cvtT<<<dim3(H / 32, D / 32, G), cb, 0, stream>>>(
            We1 + (size_t)c0 * D * H, wbuf, D, H, (size_t)D * H, (size_t)D * H);
        gemmS<0, 16, 2><<<gSH, 512, 0, stream>>>(
            xbf, 0, D, wbuf, (size_t)D * H, be1 + (size_t)c0 * H, H,
            hA, (size_t)B * H, H);
        // enc2
        cvtT<<<dim3(H / 32, H / 32, G), cb, 0, stream>>>(
            We2 + (size_t)c0 * H * H, wbuf, H, H, (size_t)H * H, (size_t)H * H);
        gemmS<0, 32, 2><<<gSH, 512, 0, stream>>>(
            hA, (size_t)B * H, H, wbuf, (size_t)H * H, be2 + (size_t)c0 * H, H,
            hB, (size_t)B * H, H);
        // enc3
        cvtT<<<dim3(H / 32, H / 32, G), cb, 0, stream>>>(
            We3 + (size_t)c0 * H * H, wbuf, H, H, (size_t)H * H, (size_t)H * H);
        gemmS<0, 32, 2><<<gSH, 512, 0, stream>>>(
            hB, (size_t)B * H, H, wbuf, (size_t)H * H, be3 + (size_t)c0 * H, H,
            hA, (size_t)B * H, H);
        // enc4 -> z (fp32 to d_out, bf16 to ws) — 2-phase kernel (N=64)
        cvtT<<<dim3(L / 32, H / 32, G), cb, 0, stream>>>(
            We4 + (size_t)c0 * H * L, wbuf, H, L, (size_t)H * L, (size_t)H * L);
        mfma_gemm<64, 1><<<dim3(32, 1, G), 256, 0, stream>>>(
            hA, (size_t)B * H, H, H, wbuf, (size_t)H * L, be4 + (size_t)c0 * L, L,
            zbf + (size_t)c0 * B * L, (size_t)B * L, L, zfp, c0);
        // dec1: [B,64] x [64,1024] -> hB (ELU) — 2-phase kernel (K=64)
        cvtT<<<dim3(H / 32, L / 32, G), cb, 0, stream>>>(
            Wd1 + (size_t)c0 * L * H, wbuf, L, H, (size_t)L * H, (size_t)L * H);
        mfma_gemm<128, 0><<<dim3(32, 8, G), 256, 0, stream>>>(
            zbf + (size_t)c0 * B * L, (size_t)B * L, L, L, wbuf, (size_t)L * H,
            bd1 + (size_t)c0 * H, H, hB, (size_t)B * H, H, nullptr, 0);
        // dec2
        cvtT<<<dim3(H / 32, H / 32, G), cb, 0, stream>>>(
            Wd2 + (size_t)c0 * H * H, wbuf, H, H, (size_t)H * H, (size_t)H * H);
        gemmS<0, 32, 2><<<gSH, 512, 0, stream>>>(
            hB, (size_t)B * H, H, wbuf, (size_t)H * H, bd2 + (size_t)c0 * H, H,
            hA, (size_t)B * H, H);
        // dec3
        cvtT<<<dim3(H / 32, H / 32, G), cb, 0, stream>>>(
            Wd3 + (size_t)c0 * H * H, wbuf, H, H, (size_t)H * H, (size_t)H * H);
        gemmS<0, 32, 2><<<gSH, 512, 0, stream>>>(
            hA, (size_t)B * H, H, wbuf, (size_t)H * H, bd3 + (size_t)c0 * H, H,
            hB, (size_t)B * H, H);
        // dec4 -> x_recons (bf16), N=512
        cvtT<<<dim3(D / 32, H / 32, G), cb, 0, stream>>>(
            Wd4 + (size_t)c0 * H * D, wbuf, H, D, (size_t)H * D, (size_t)H * D);
        gemmS<2, 32, 1><<<gSD, 512, 0, stream>>>(
            hB, (size_t)B * H, H, wbuf, (size_t)H * D, bd4 + (size_t)c0 * D, D,
            xrec, (size_t)B * D, D);
        // fused recon_x accumulation + recon_errors
        recon_group<<<B / 4, 256, 0, stream>>>(x, xrec, p, recon_x, err, c0, G);
    }

    losses_rows<<<B / 256, 256, 0, stream>>>(p, err, acc, B);
    mse_reduce<<<1024, 256, 0, stream>>>(recon_x, x, acc, B * D);
    finalize_kernel<<<1, 1, 0, stream>>>(acc, scal, B, D);
}

// Round 11
// 606.147 us; speedup vs baseline: 8.4428x; 8.4428x over previous
//
#include <hip/hip_runtime.h>
#include <hip/hip_bf16.h>

typedef unsigned short ushort_t;
typedef __bf16 bf16x8 __attribute__((ext_vector_type(8)));
typedef float f32x4 __attribute__((ext_vector_type(4)));

__device__ __forceinline__ void gload_lds16(const void* g, void* l) {
    __builtin_amdgcn_global_load_lds(
        (const __attribute__((address_space(1))) void*)g,
        (__attribute__((address_space(3))) void*)l, 16, 0, 0);
}

__device__ __forceinline__ float elu1(float v) { return v > 0.f ? v : expm1f(v); }

// stage [256 rows][32 k] bf16 (16 KiB): 2 loads/thread (512 thr). LDS dest
// linear (t*16B), global source pre-swizzled: chunk bit1 ^= row bit3.
__device__ __forceinline__ void stage_half256(const ushort_t* g, int ldg,
                                              ushort_t* lds, int t) {
    const int row = t >> 2;
    const int chunk = (t & 3) ^ ((t >> 4) & 2);
    const ushort_t* src = g + (size_t)row * ldg + chunk * 8;
    const int wo = (t >> 6) * 512;
    gload_lds16(src, lds + wo);
    gload_lds16(src + (size_t)128 * ldg, lds + 4096 + wo);
}
// stage [128 rows][32 k] (8 KiB): 1 load/thread
__device__ __forceinline__ void stage_half128(const ushort_t* g, int ldg,
                                              ushort_t* lds, int t) {
    const int row = t >> 2;
    const int chunk = (t & 3) ^ ((t >> 4) & 2);
    gload_lds16(g + (size_t)row * ldg + chunk * 8, lds + (t >> 6) * 512);
}

// ---------------------------------------------------------------------------
// 128x256 MFMA GEMM, BK=32, 8 waves (2M x 4N), 64x64/wave (acc[4][4]).
// R9 champion mechanics: ONE barrier/kt, compiler lgkm waits, counted
// vmcnt(3), 3-deep rotation w/ STATIC buffer offsets (unroll-by-3).
// R11 change: bn in LOW bits of block index (L2: B-panel resident, A-row
// fetched once by its bn-siblings). LDS (ushorts): A @ 0,4096,8192 ;
// B @ 12288,20480,28672.
// ---------------------------------------------------------------------------
#define LDA(J_, MI_) (*(const bf16x8*)(LDSc + vA + ((J_) * 8192 + (MI_) * 1024)))
#define LDB(J_, NI_) (*(const bf16x8*)(LDSc + vB + ((J_) * 16384 + (NI_) * 1024)))

#define GBODY(J_)                                                              \
  {                                                                            \
    bf16x8 a0 = LDA(J_, 0), a1 = LDA(J_, 1), a2 = LDA(J_, 2), a3 = LDA(J_, 3); \
    bf16x8 b0 = LDB(J_, 0), b1 = LDB(J_, 1), b2 = LDB(J_, 2), b3 = LDB(J_, 3); \
    if (kt + 2 < NT) {                                                         \
      constexpr int W_ = ((J_) + 2) % 3;                                       \
      stage_half256(Btile + (size_t)(kt + 2) * 32, K, &LDS[12288 + W_ * 8192], t); \
      stage_half128(Atile + (size_t)(kt + 2) * 32, lda, &LDS[W_ * 4096], t);   \
    }                                                                          \
    __builtin_amdgcn_s_setprio(1);                                             \
    acc[0][0] = __builtin_amdgcn_mfma_f32_16x16x32_bf16(a0, b0, acc[0][0], 0, 0, 0); \
    acc[0][1] = __builtin_amdgcn_mfma_f32_16x16x32_bf16(a0, b1, acc[0][1], 0, 0, 0); \
    acc[0][2] = __builtin_amdgcn_mfma_f32_16x16x32_bf16(a0, b2, acc[0][2], 0, 0, 0); \
    acc[0][3] = __builtin_amdgcn_mfma_f32_16x16x32_bf16(a0, b3, acc[0][3], 0, 0, 0); \
    acc[1][0] = __builtin_amdgcn_mfma_f32_16x16x32_bf16(a1, b0, acc[1][0], 0, 0, 0); \
    acc[1][1] = __builtin_amdgcn_mfma_f32_16x16x32_bf16(a1, b1, acc[1][1], 0, 0, 0); \
    acc[1][2] = __builtin_amdgcn_mfma_f32_16x16x32_bf16(a1, b2, acc[1][2], 0, 0, 0); \
    acc[1][3] = __builtin_amdgcn_mfma_f32_16x16x32_bf16(a1, b3, acc[1][3], 0, 0, 0); \
    acc[2][0] = __builtin_amdgcn_mfma_f32_16x16x32_bf16(a2, b0, acc[2][0], 0, 0, 0); \
    acc[2][1] = __builtin_amdgcn_mfma_f32_16x16x32_bf16(a2, b1, acc[2][1], 0, 0, 0); \
    acc[2][2] = __builtin_amdgcn_mfma_f32_16x16x32_bf16(a2, b2, acc[2][2], 0, 0, 0); \
    acc[2][3] = __builtin_amdgcn_mfma_f32_16x16x32_bf16(a2, b3, acc[2][3], 0, 0, 0); \
    acc[3][0] = __builtin_amdgcn_mfma_f32_16x16x32_bf16(a3, b0, acc[3][0], 0, 0, 0); \
    acc[3][1] = __builtin_amdgcn_mfma_f32_16x16x32_bf16(a3, b1, acc[3][1], 0, 0, 0); \
    acc[3][2] = __builtin_amdgcn_mfma_f32_16x16x32_bf16(a3, b2, acc[3][2], 0, 0, 0); \
    acc[3][3] = __builtin_amdgcn_mfma_f32_16x16x32_bf16(a3, b3, acc[3][3], 0, 0, 0); \
    __builtin_amdgcn_s_setprio(0);                                             \
    if (kt < NT - 2) asm volatile("s_waitcnt vmcnt(3)" ::: "memory");          \
    else             asm volatile("s_waitcnt vmcnt(0)" ::: "memory");          \
    __builtin_amdgcn_s_barrier();                                              \
    asm volatile("" ::: "memory");                                             \
    ++kt;                                                                      \
  }

template<int MODE, int NT, int LNB>
__global__ __launch_bounds__(512, 4) void gemmS(
    const __hip_bfloat16* __restrict__ A, size_t sAc, int lda,
    const __hip_bfloat16* __restrict__ Wt, size_t sWc,
    const float* __restrict__ bias, int sBc,
    __hip_bfloat16* __restrict__ Obf, size_t sOc, int ldo)
{
    constexpr int K = NT * 32;
    __shared__ __align__(16) ushort_t LDS[36864];   // 72 KiB

    const int t = threadIdx.x;
    const int wid = t >> 6, lane = t & 63;
    const int wm = wid >> 2, wn = wid & 3;
    const int fl = lane & 15, fh = lane >> 4;

    // bijective XCD swizzle: orig%8 -> XCD gets a contiguous chunk (= 1 chart).
    // bn in LOW bits of inner: the LNB bn-siblings of each bm co-resident ->
    // B-panel L2-resident, each A block-row fetched once.
    const int orig = blockIdx.x + 32 * blockIdx.y + (32 << LNB) * blockIdx.z;
    const int q = (32 << LNB);                 // nwg/8 (gridDim.z == 8)
    const int wg = (orig & 7) * q + (orig >> 3);
    const int z = wg >> (5 + LNB);
    const int inner = wg & ((32 << LNB) - 1);
    const int bm = (inner >> LNB) * 128;
    const int bn = (inner & ((1 << LNB) - 1)) * 256;

    const ushort_t* Atile = (const ushort_t*)A + (size_t)z * sAc + (size_t)bm * lda;
    const ushort_t* Btile = (const ushort_t*)Wt + (size_t)z * sWc + (size_t)bn * K;

    // per-lane LDS read addresses; swizzle reduced to lane-only form:
    // (r>>2)&2 == (fl>>2)&2 for r = 64*w + 16*frag + fl (frag-independent).
    const char* LDSc = (const char*)&LDS[0];
    const unsigned lanepart = fl * 64 + ((fh ^ ((fl >> 2) & 2)) << 4);
    const unsigned vA = wm * 4096 + lanepart;
    const unsigned vB = 24576 + wn * 4096 + lanepart;

    f32x4 acc[4][4];
    #pragma unroll
    for (int i = 0; i < 4; ++i)
        #pragma unroll
        for (int j = 0; j < 4; ++j) acc[i][j] = (f32x4){0.f, 0.f, 0.f, 0.f};

    // prologue: stage kt0 -> buf0, kt1 -> buf1 (6 loads); wait kt0's 3
    stage_half256(Btile, K, &LDS[12288], t);
    stage_half128(Atile, lda, &LDS[0], t);
    stage_half256(Btile + 32, K, &LDS[12288 + 8192], t);
    stage_half128(Atile + 32, lda, &LDS[4096], t);
    asm volatile("s_waitcnt vmcnt(3)" ::: "memory");
    __builtin_amdgcn_s_barrier();
    asm volatile("" ::: "memory");

    int kt = 0;
    while (kt + 3 <= NT) { GBODY(0) GBODY(1) GBODY(2) }
    if constexpr (NT % 3 >= 1) { GBODY(0) }
    if constexpr (NT % 3 >= 2) { GBODY(1) }

    // epilogue: C/D layout col=lane&15, row=(lane>>4)*4+reg
    #pragma unroll
    for (int mi = 0; mi < 4; ++mi) {
        #pragma unroll
        for (int ni = 0; ni < 4; ++ni) {
            const int n = bn + wn * 64 + ni * 16 + fl;
            const float bv = bias[z * sBc + n];
            #pragma unroll
            for (int r = 0; r < 4; ++r) {
                const int m = bm + wm * 64 + mi * 16 + fh * 4 + r;
                float v = acc[mi][ni][r] + bv;
                if (MODE == 0) v = elu1(v);
                Obf[(size_t)z * sOc + (size_t)m * ldo + n] = __float2bfloat16(v);
            }
        }
    }
}

// ---------------------------------------------------------------------------
// 2-phase 128xBN kernel (round-2, proven) — for enc4 (N=64) / dec1 (K=64)
// ---------------------------------------------------------------------------
template<int BN, int MODE>
__global__ __launch_bounds__(256) void mfma_gemm(
    const __hip_bfloat16* __restrict__ A, size_t sAc, int lda, int K,
    const __hip_bfloat16* __restrict__ Wt, size_t sWc,
    const float* __restrict__ bias, int sBc,
    __hip_bfloat16* __restrict__ Obf, size_t sOc, int ldo,
    float* __restrict__ Of, int c0)
{
    constexpr int NI = BN / 32;
    __shared__ __align__(16) ushort_t As2[128 * 32];
    __shared__ __align__(16) ushort_t Bs2[BN * 32];

    const int t = threadIdx.x;
    const int wid = t >> 6, lane = t & 63;
    const int wm = wid >> 1, wn = wid & 1;
    const int z = blockIdx.z;
    const int bm = blockIdx.x * 128;
    const int bn = blockIdx.y * BN;

    const ushort_t* Ap = (const ushort_t*)A + (size_t)z * sAc;
    const ushort_t* Wp = (const ushort_t*)Wt + (size_t)z * sWc;

    const int srow = t >> 2;
    const int scol = (t & 3) << 3;
    const int fl = lane & 15, fh = lane >> 4;

    f32x4 zero4 = {0.f, 0.f, 0.f, 0.f};
    f32x4 acc[4][NI];
    #pragma unroll
    for (int mi = 0; mi < 4; ++mi)
        #pragma unroll
        for (int ni = 0; ni < NI; ++ni) acc[mi][ni] = zero4;

    for (int k0 = 0; k0 < K; k0 += 32) {
        #pragma unroll
        for (int i = 0; i < 2; ++i)
            gload_lds16(Ap + (size_t)(bm + i * 64 + srow) * lda + k0 + scol,
                        &As2[i * 2048 + wid * 512]);
        #pragma unroll
        for (int i = 0; i < BN / 64; ++i)
            gload_lds16(Wp + (size_t)(bn + i * 64 + srow) * K + k0 + scol,
                        &Bs2[i * 2048 + wid * 512]);
        __syncthreads();

        bf16x8 af[4], bfr[NI];
        #pragma unroll
        for (int mi = 0; mi < 4; ++mi)
            af[mi] = *(const bf16x8*)&As2[(wm * 64 + mi * 16 + fl) * 32 + fh * 8];
        #pragma unroll
        for (int ni = 0; ni < NI; ++ni)
            bfr[ni] = *(const bf16x8*)&Bs2[(wn * (BN / 2) + ni * 16 + fl) * 32 + fh * 8];
        #pragma unroll
        for (int mi = 0; mi < 4; ++mi)
            #pragma unroll
            for (int ni = 0; ni < NI; ++ni)
                acc[mi][ni] = __builtin_amdgcn_mfma_f32_16x16x32_bf16(
                    af[mi], bfr[ni], acc[mi][ni], 0, 0, 0);
        __syncthreads();
    }

    #pragma unroll
    for (int mi = 0; mi < 4; ++mi) {
        #pragma unroll
        for (int ni = 0; ni < NI; ++ni) {
            const int n = bn + wn * (BN / 2) + ni * 16 + fl;
            const float bv = bias[z * sBc + n];
            #pragma unroll
            for (int r = 0; r < 4; ++r) {
                const int m = bm + wm * 64 + mi * 16 + fh * 4 + r;
                float v = acc[mi][ni][r] + bv;
                if (MODE == 0) v = elu1(v);
                Obf[(size_t)z * sOc + (size_t)m * ldo + n] = __float2bfloat16(v);
                if (MODE == 1)
                    Of[(size_t)m * 512 + (size_t)(c0 + z) * 64 + n] = v;
            }
        }
    }
}

// fp32 [K][N] -> bf16 [N][K] (transpose + convert)
__global__ __launch_bounds__(256) void cvtT(
    const float* __restrict__ in, __hip_bfloat16* __restrict__ out,
    int K, int N, size_t sInC, size_t sOutC)
{
    __shared__ float tile[32][33];
    const float* ip = in + blockIdx.z * sInC;
    __hip_bfloat16* op = out + blockIdx.z * sOutC;
    const int n0 = blockIdx.x * 32, k0 = blockIdx.y * 32;
    const int x = threadIdx.x, y = threadIdx.y;
    #pragma unroll
    for (int j = 0; j < 4; ++j)
        tile[y + 8 * j][x] = ip[(size_t)(k0 + y + 8 * j) * N + n0 + x];
    __syncthreads();
    #pragma unroll
    for (int j = 0; j < 4; ++j)
        op[(size_t)(n0 + y + 8 * j) * K + k0 + x] = __float2bfloat16(tile[x][y + 8 * j]);
}

__global__ __launch_bounds__(256) void cvtx(
    const float* __restrict__ in, __hip_bfloat16* __restrict__ out, int n4)
{
    int i = blockIdx.x * 256 + threadIdx.x;
    if (i < n4) {
        float4 v = ((const float4*)in)[i];
        out[i * 4 + 0] = __float2bfloat16(v.x);
        out[i * 4 + 1] = __float2bfloat16(v.y);
        out[i * 4 + 2] = __float2bfloat16(v.z);
        out[i * 4 + 3] = __float2bfloat16(v.w);
    }
}

__global__ __launch_bounds__(256) void recon_group(
    const float* __restrict__ x, const __hip_bfloat16* __restrict__ xrec,
    const float* __restrict__ p, float* __restrict__ recon_x,
    float* __restrict__ err, int c0, int G)
{
    const int wid = threadIdx.x >> 6, lane = threadIdx.x & 63;
    const size_t b = (size_t)blockIdx.x * 4 + wid;
    const float4* xp = (const float4*)(x + b * 512);
    const float4 x0 = xp[lane * 2], x1 = xp[lane * 2 + 1];
    const float xv[8] = {x0.x, x0.y, x0.z, x0.w, x1.x, x1.y, x1.z, x1.w};
    float r[8] = {0.f, 0.f, 0.f, 0.f, 0.f, 0.f, 0.f, 0.f};

    for (int cc = 0; cc < G; ++cc) {
        const ushort_t* xr =
            (const ushort_t*)xrec + ((size_t)cc * 4096 + b) * 512 + lane * 8;
        bf16x8 v = *(const bf16x8*)xr;
        float pv = p[b * 8 + c0 + cc];
        float e = 0.f;
        #pragma unroll
        for (int j = 0; j < 8; ++j) {
            float f = (float)v[j];
            r[j] = fmaf(pv, f, r[j]);
            float d = xv[j] - f;
            e = fmaf(d, d, e);
        }
        #pragma unroll
        for (int off = 1; off < 64; off <<= 1) e += __shfl_xor(e, off, 64);
        if (lane == 0) err[b * 8 + c0 + cc] = e;
    }

    float4* op = (float4*)(recon_x + b * 512);
    float4 o0 = {r[0], r[1], r[2], r[3]}, o1 = {r[4], r[5], r[6], r[7]};
    if (c0) {
        float4 t0 = op[lane * 2], t1 = op[lane * 2 + 1];
        o0.x += t0.x; o0.y += t0.y; o0.z += t0.z; o0.w += t0.w;
        o1.x += t1.x; o1.y += t1.y; o1.z += t1.z; o1.w += t1.w;
    }
    op[lane * 2] = o0;
    op[lane * 2 + 1] = o1;
}

__global__ __launch_bounds__(256) void proj_sparsemax(
    const float* __restrict__ x, const float* __restrict__ Wp,
    const float* __restrict__ bp, float* __restrict__ p, int B, int D)
{
    int gw = (blockIdx.x * blockDim.x + threadIdx.x) >> 6;
    int lane = threadIdx.x & 63;
    if (gw >= B) return;
    const float* xr = x + (size_t)gw * D;
    float acc[8] = {0.f, 0.f, 0.f, 0.f, 0.f, 0.f, 0.f, 0.f};
    for (int d = lane; d < D; d += 64) {
        float xv = xr[d];
        #pragma unroll
        for (int c = 0; c < 8; ++c) acc[c] = fmaf(xv, Wp[d * 8 + c], acc[c]);
    }
    #pragma unroll
    for (int off = 32; off > 0; off >>= 1) {
        #pragma unroll
        for (int c = 0; c < 8; ++c) acc[c] += __shfl_xor(acc[c], off, 64);
    }
    if (lane == 0) {
        float s[8], zs[8];
        #pragma unroll
        for (int c = 0; c < 8; ++c) { s[c] = acc[c] + bp[c]; zs[c] = s[c]; }
        for (int i = 1; i < 8; ++i) {
            float v = zs[i];
            int j = i - 1;
            while (j >= 0 && zs[j] < v) { zs[j + 1] = zs[j]; --j; }
            zs[j + 1] = v;
        }
        float cs = 0.f, csel = 1.f;
        int kz = 1;
        for (int k = 1; k <= 8; ++k) {
            cs += zs[k - 1];
            if (1.f + (float)k * zs[k - 1] > cs) { kz = k; csel = cs; }
        }
        float tau = (csel - 1.f) / (float)kz;
        #pragma unroll
        for (int c = 0; c < 8; ++c) p[gw * 8 + c] = fmaxf(s[c] - tau, 0.f);
    }
}

__global__ __launch_bounds__(256) void losses_rows(
    const float* __restrict__ p, const float* __restrict__ err,
    float* __restrict__ acc, int B)
{
    __shared__ float s[10];
    int t = threadIdx.x;
    if (t < 10) s[t] = 0.f;
    __syncthreads();
    int b = blockIdx.x * 256 + t;
    if (b < B) {
        float pr[8], er[8];
        #pragma unroll
        for (int c = 0; c < 8; ++c) { pr[c] = p[b * 8 + c]; er[c] = err[b * 8 + c]; }
        float mn = er[0];
        #pragma unroll
        for (int c = 1; c < 8; ++c) mn = fminf(mn, er[c]);
        float q[8], se = 0.f;
        #pragma unroll
        for (int c = 0; c < 8; ++c) { q[c] = expf(mn - er[c]); se += q[c]; }
        float rl = 0.f, tl = 0.f;
        #pragma unroll
        for (int c = 0; c < 8; ++c) {
            rl = fmaf(pr[c], er[c], rl);
            tl = fmaf(q[c] / se, logf(pr[c] + 1e-8f), tl);
        }
        atomicAdd(&s[0], rl);
        atomicAdd(&s[1], tl);
        #pragma unroll
        for (int c = 0; c < 8; ++c) atomicAdd(&s[2 + c], pr[c]);
    }
    __syncthreads();
    if (t < 10) atomicAdd(&acc[t], s[t]);
}

__global__ __launch_bounds__(256) void mse_reduce(
    const float* __restrict__ recon_x, const float* __restrict__ x,
    float* __restrict__ acc, int n)
{
    float sm = 0.f;
    for (int i = blockIdx.x * 256 + threadIdx.x; i < n; i += gridDim.x * 256) {
        float d = recon_x[i] - x[i];
        sm = fmaf(d, d, sm);
    }
    __shared__ float sh;
    if (threadIdx.x == 0) sh = 0.f;
    __syncthreads();
    atomicAdd(&sh, sm);
    __syncthreads();
    if (threadIdx.x == 0) atomicAdd(&acc[10], sh);
}

__global__ void finalize_kernel(const float* __restrict__ acc,
                                float* __restrict__ scal, int B, int D)
{
    float invB = 1.f / (float)B;
    float recon = acc[0] * invB;
    float trans = -acc[1] * invB;
    float nondom = 0.f;
    for (int c = 0; c < 8; ++c) {
        float mp = acc[2 + c] * invB;
        float d = mp - 0.125f;
        nondom = fmaf(d, d, nondom);
    }
    float mse = acc[10] / ((float)B * (float)D);
    scal[0] = recon + trans + nondom;
    scal[1] = recon;
    scal[2] = nondom;
    scal[3] = trans;
    scal[4] = mse;
}

extern "C" void kernel_launch(void* const* d_in, const int* in_sizes, int n_in,
                              void* d_out, int out_size, void* d_ws, size_t ws_size,
                              hipStream_t stream)
{
    const int B = 4096, D = 512, L = 64, H = 1024, C = 8;

    const float* x   = (const float*)d_in[0];
    const float* We1 = (const float*)d_in[1];
    const float* be1 = (const float*)d_in[2];
    const float* We2 = (const float*)d_in[3];
    const float* be2 = (const float*)d_in[4];
    const float* We3 = (const float*)d_in[5];
    const float* be3 = (const float*)d_in[6];
    const float* We4 = (const float*)d_in[7];
    const float* be4 = (const float*)d_in[8];
    const float* Wd1 = (const float*)d_in[9];
    const float* bd1 = (const float*)d_in[10];
    const float* Wd2 = (const float*)d_in[11];
    const float* bd2 = (const float*)d_in[12];
    const float* Wd3 = (const float*)d_in[13];
    const float* bd3 = (const float*)d_in[14];
    const float* Wd4 = (const float*)d_in[15];
    const float* bd4 = (const float*)d_in[16];
    const float* Wp  = (const float*)d_in[17];
    const float* bp  = (const float*)d_in[18];

    float* out     = (float*)d_out;
    float* recon_x = out;                          // [B,D]
    float* zfp     = out + (size_t)B * D;          // [B,C,L]
    float* p       = zfp + (size_t)B * C * L;      // [B,C]
    float* scal    = p + (size_t)B * C;            // 5 scalars

    const size_t perG = ((size_t)H * H + 2ull * B * H + (size_t)B * D) * 2ull;
    const size_t fixedB = ((size_t)B * D + (size_t)C * B * L) * 2ull +
                          ((size_t)B * C + 16) * 4ull + 1024;
    int G = 8;
    while (G > 1 && fixedB + perG * (size_t)G > ws_size) G >>= 1;

    char* w = (char*)d_ws;
    __hip_bfloat16* xbf  = (__hip_bfloat16*)w; w += (size_t)B * D * 2;
    __hip_bfloat16* zbf  = (__hip_bfloat16*)w; w += (size_t)C * B * L * 2;
    __hip_bfloat16* wbuf = (__hip_bfloat16*)w; w += (size_t)G * H * H * 2;
    __hip_bfloat16* hA   = (__hip_bfloat16*)w; w += (size_t)G * B * H * 2;
    __hip_bfloat16* hB   = (__hip_bfloat16*)w; w += (size_t)G * B * H * 2;
    __hip_bfloat16* xrec = (__hip_bfloat16*)w; w += (size_t)G * B * D * 2;
    float* err = (float*)w; w += (size_t)B * C * 4;
    float* acc = (float*)w;

    hipMemsetAsync(acc, 0, 16 * sizeof(float), stream);

    cvtx<<<(B * D / 4 + 255) / 256, 256, 0, stream>>>(x, xbf, B * D / 4);
    proj_sparsemax<<<B / 4, 256, 0, stream>>>(x, Wp, bp, p, B, D);

    const dim3 cb(32, 8);
    const dim3 gSH(32, 4, 8);   // 128x256 tiles, N=1024
    const dim3 gSD(32, 2, 8);   // N=512

    for (int c0 = 0; c0 < C; c0 += G) {
        // enc1: [B,512] x [512,1024] -> hA (ELU), K=512 -> NT=16
        cvtT<<<dim3(H / 32, D / 32, G), cb, 0, stream>>>(
            We1 + (size_t)c0 * D * H, wbuf, D, H, (size_t)D * H, (size_t)D * H);
        gemmS<0, 16, 2><<<gSH, 512, 0, stream>>>(
            xbf, 0, D, wbuf, (size_t)D * H, be1 + (size_t)c0 * H, H,
            hA, (size_t)B * H, H);
        // enc2
        cvtT<<<dim3(H / 32, H / 32, G), cb, 0, stream>>>(
            We2 + (size_t)c0 * H * H, wbuf, H, H, (size_t)H * H, (size_t)H * H);
        gemmS<0, 32, 2><<<gSH, 512, 0, stream>>>(
            hA, (size_t)B * H, H, wbuf, (size_t)H * H, be2 + (size_t)c0 * H, H,
            hB, (size_t)B * H, H);
        // enc3
        cvtT<<<dim3(H / 32, H / 32, G), cb, 0, stream>>>(
            We3 + (size_t)c0 * H * H, wbuf, H, H, (size_t)H * H, (size_t)H * H);
        gemmS<0, 32, 2><<<gSH, 512, 0, stream>>>(
            hB, (size_t)B * H, H, wbuf, (size_t)H * H, be3 + (size_t)c0 * H, H,
            hA, (size_t)B * H, H);
        // enc4 -> z (fp32 to d_out, bf16 to ws) — 2-phase kernel (N=64)
        cvtT<<<dim3(L / 32, H / 32, G), cb, 0, stream>>>(
            We4 + (size_t)c0 * H * L, wbuf, H, L, (size_t)H * L, (size_t)H * L);
        mfma_gemm<64, 1><<<dim3(32, 1, G), 256, 0, stream>>>(
            hA, (size_t)B * H, H, H, wbuf, (size_t)H * L, be4 + (size_t)c0 * L, L,
            zbf + (size_t)c0 * B * L, (size_t)B * L, L, zfp, c0);
        // dec1: [B,64] x [64,1024] -> hB (ELU) — 2-phase kernel (K=64)
        cvtT<<<dim3(H / 32, L / 32, G), cb, 0, stream>>>(
            Wd1 + (size_t)c0 * L * H, wbuf, L, H, (size_t)L * H, (size_t)L * H);
        mfma_gemm<128, 0><<<dim3(32, 8, G), 256, 0, stream>>>(
            zbf + (size_t)c0 * B * L, (size_t)B * L, L, L, wbuf, (size_t)L * H,
            bd1 + (size_t)c0 * H, H, hB, (size_t)B * H, H, nullptr, 0);
        // dec2
        cvtT<<<dim3(H / 32, H / 32, G), cb, 0, stream>>>(
            Wd2 + (size_t)c0 * H * H, wbuf, H, H, (size_t)H * H, (size_t)H * H);
        gemmS<0, 32, 2><<<gSH, 512, 0, stream>>>(
            hB, (size_t)B * H, H, wbuf, (size_t)H * H, bd2 + (size_t)c0 * H, H,
            hA, (size_t)B * H, H);
        // dec3
        cvtT<<<dim3(H / 32, H / 32, G), cb, 0, stream>>>(
            Wd3 + (size_t)c0 * H * H, wbuf, H, H, (size_t)H * H, (size_t)H * H);
        gemmS<0, 32, 2><<<gSH, 512, 0, stream>>>(
            hA, (size_t)B * H, H, wbuf, (size_t)H * H, bd3 + (size_t)c0 * H, H,
            hB, (size_t)B * H, H);
        // dec4 -> x_recons (bf16), N=512
        cvtT<<<dim3(D / 32, H / 32, G), cb, 0, stream>>>(
            Wd4 + (size_t)c0 * H * D, wbuf, H, D, (size_t)H * D, (size_t)H * D);
        gemmS<2, 32, 1><<<gSD, 512, 0, stream>>>(
            hB, (size_t)B * H, H, wbuf, (size_t)H * D, bd4 + (size_t)c0 * D, D,
            xrec, (size_t)B * D, D);
        // fused recon_x accumulation + recon_errors
        recon_group<<<B / 4, 256, 0, stream>>>(x, xrec, p, recon_x, err, c0, G);
    }

    losses_rows<<<B / 256, 256, 0, stream>>>(p, err, acc, B);
    mse_reduce<<<1024, 256, 0, stream>>>(recon_x, x, acc, B * D);
    finalize_kernel<<<1, 1, 0, stream>>>(acc, scal, B, D);
}

// Round 12
// 598.922 us; speedup vs baseline: 8.5446x; 1.0121x over previous
//
#include <hip/hip_runtime.h>
#include <hip/hip_bf16.h>

typedef unsigned short ushort_t;
typedef __bf16 bf16x8 __attribute__((ext_vector_type(8)));
typedef float f32x4 __attribute__((ext_vector_type(4)));

__device__ __forceinline__ void gload_lds16(const void* g, void* l) {
    __builtin_amdgcn_global_load_lds(
        (const __attribute__((address_space(1))) void*)g,
        (__attribute__((address_space(3))) void*)l, 16, 0, 0);
}

__device__ __forceinline__ float elu1(float v) { return v > 0.f ? v : expm1f(v); }

// stage [256 rows][32 k] bf16 (16 KiB): 2 loads/thread (512 thr). LDS dest
// linear (t*16B), global source pre-swizzled: chunk bit1 ^= row bit3.
__device__ __forceinline__ void stage_half256(const ushort_t* g, int ldg,
                                              ushort_t* lds, int t) {
    const int row = t >> 2;
    const int chunk = (t & 3) ^ ((t >> 4) & 2);
    const ushort_t* src = g + (size_t)row * ldg + chunk * 8;
    const int wo = (t >> 6) * 512;
    gload_lds16(src, lds + wo);
    gload_lds16(src + (size_t)128 * ldg, lds + 4096 + wo);
}
// stage [128 rows][32 k] (8 KiB): 1 load/thread
__device__ __forceinline__ void stage_half128(const ushort_t* g, int ldg,
                                              ushort_t* lds, int t) {
    const int row = t >> 2;
    const int chunk = (t & 3) ^ ((t >> 4) & 2);
    gload_lds16(g + (size_t)row * ldg + chunk * 8, lds + (t >> 6) * 512);
}

// ---------------------------------------------------------------------------
// 128x256 MFMA GEMM, BK=32, 8 waves (2M x 4N), 64x64/wave (acc[4][4]).
// R11 mechanics (ONE barrier/kt, compiler lgkm waits, bn-low L2 ordering,
// lane-only swizzle) with 2-deep LDS rotation (48 KiB) -> 3 blocks/CU.
// launch_bounds kept at (512,4): compiler VGPR budget unchanged (64);
// occupancy raised purely via the hardware LDS limit (R10 post-mortem).
// LDS (ushorts): A bufs @ 0,4096 ; B bufs @ 8192,16384.
// ---------------------------------------------------------------------------
#define LDA(J_, MI_) (*(const bf16x8*)(LDSc + vA + ((J_) * 8192 + (MI_) * 1024)))
#define LDB(J_, NI_) (*(const bf16x8*)(LDSc + vB + ((J_) * 16384 + (NI_) * 1024)))

#define GBODY(J_)                                                              \
  {                                                                            \
    bf16x8 a0 = LDA(J_, 0), a1 = LDA(J_, 1), a2 = LDA(J_, 2), a3 = LDA(J_, 3); \
    bf16x8 b0 = LDB(J_, 0), b1 = LDB(J_, 1), b2 = LDB(J_, 2), b3 = LDB(J_, 3); \
    if (kt + 1 < NT) {                                                         \
      stage_half256(Btile + (size_t)(kt + 1) * 32, K, &LDS[8192 + ((J_) ^ 1) * 8192], t); \
      stage_half128(Atile + (size_t)(kt + 1) * 32, lda, &LDS[((J_) ^ 1) * 4096], t); \
    }                                                                          \
    __builtin_amdgcn_s_setprio(1);                                             \
    acc[0][0] = __builtin_amdgcn_mfma_f32_16x16x32_bf16(a0, b0, acc[0][0], 0, 0, 0); \
    acc[0][1] = __builtin_amdgcn_mfma_f32_16x16x32_bf16(a0, b1, acc[0][1], 0, 0, 0); \
    acc[0][2] = __builtin_amdgcn_mfma_f32_16x16x32_bf16(a0, b2, acc[0][2], 0, 0, 0); \
    acc[0][3] = __builtin_amdgcn_mfma_f32_16x16x32_bf16(a0, b3, acc[0][3], 0, 0, 0); \
    acc[1][0] = __builtin_amdgcn_mfma_f32_16x16x32_bf16(a1, b0, acc[1][0], 0, 0, 0); \
    acc[1][1] = __builtin_amdgcn_mfma_f32_16x16x32_bf16(a1, b1, acc[1][1], 0, 0, 0); \
    acc[1][2] = __builtin_amdgcn_mfma_f32_16x16x32_bf16(a1, b2, acc[1][2], 0, 0, 0); \
    acc[1][3] = __builtin_amdgcn_mfma_f32_16x16x32_bf16(a1, b3, acc[1][3], 0, 0, 0); \
    acc[2][0] = __builtin_amdgcn_mfma_f32_16x16x32_bf16(a2, b0, acc[2][0], 0, 0, 0); \
    acc[2][1] = __builtin_amdgcn_mfma_f32_16x16x32_bf16(a2, b1, acc[2][1], 0, 0, 0); \
    acc[2][2] = __builtin_amdgcn_mfma_f32_16x16x32_bf16(a2, b2, acc[2][2], 0, 0, 0); \
    acc[2][3] = __builtin_amdgcn_mfma_f32_16x16x32_bf16(a2, b3, acc[2][3], 0, 0, 0); \
    acc[3][0] = __builtin_amdgcn_mfma_f32_16x16x32_bf16(a3, b0, acc[3][0], 0, 0, 0); \
    acc[3][1] = __builtin_amdgcn_mfma_f32_16x16x32_bf16(a3, b1, acc[3][1], 0, 0, 0); \
    acc[3][2] = __builtin_amdgcn_mfma_f32_16x16x32_bf16(a3, b2, acc[3][2], 0, 0, 0); \
    acc[3][3] = __builtin_amdgcn_mfma_f32_16x16x32_bf16(a3, b3, acc[3][3], 0, 0, 0); \
    __builtin_amdgcn_s_setprio(0);                                             \
    asm volatile("s_waitcnt vmcnt(0)" ::: "memory");                           \
    __builtin_amdgcn_s_barrier();                                              \
    asm volatile("" ::: "memory");                                             \
    ++kt;                                                                      \
  }

template<int MODE, int NT, int LNB>
__global__ __launch_bounds__(512, 4) void gemmS(
    const __hip_bfloat16* __restrict__ A, size_t sAc, int lda,
    const __hip_bfloat16* __restrict__ Wt, size_t sWc,
    const float* __restrict__ bias, int sBc,
    __hip_bfloat16* __restrict__ Obf, size_t sOc, int ldo)
{
    constexpr int K = NT * 32;
    __shared__ __align__(16) ushort_t LDS[24576];   // 48 KiB -> 3 blocks/CU

    const int t = threadIdx.x;
    const int wid = t >> 6, lane = t & 63;
    const int wm = wid >> 2, wn = wid & 3;
    const int fl = lane & 15, fh = lane >> 4;

    // bijective XCD swizzle: orig%8 -> XCD gets a contiguous chunk (= 1 chart).
    // bn in LOW bits of inner: the LNB bn-siblings of each bm co-resident ->
    // B-panel L2-resident, each A block-row fetched once (R11: FETCH -43%).
    const int orig = blockIdx.x + 32 * blockIdx.y + (32 << LNB) * blockIdx.z;
    const int q = (32 << LNB);                 // nwg/8 (gridDim.z == 8)
    const int wg = (orig & 7) * q + (orig >> 3);
    const int z = wg >> (5 + LNB);
    const int inner = wg & ((32 << LNB) - 1);
    const int bm = (inner >> LNB) * 128;
    const int bn = (inner & ((1 << LNB) - 1)) * 256;

    const ushort_t* Atile = (const ushort_t*)A + (size_t)z * sAc + (size_t)bm * lda;
    const ushort_t* Btile = (const ushort_t*)Wt + (size_t)z * sWc + (size_t)bn * K;

    // per-lane LDS read addresses; swizzle reduced to lane-only form:
    // (r>>2)&2 == (fl>>2)&2 for r = 64*w + 16*frag + fl (frag-independent).
    const char* LDSc = (const char*)&LDS[0];
    const unsigned lanepart = fl * 64 + ((fh ^ ((fl >> 2) & 2)) << 4);
    const unsigned vA = wm * 4096 + lanepart;
    const unsigned vB = 16384 + wn * 4096 + lanepart;

    f32x4 acc[4][4];
    #pragma unroll
    for (int i = 0; i < 4; ++i)
        #pragma unroll
        for (int j = 0; j < 4; ++j) acc[i][j] = (f32x4){0.f, 0.f, 0.f, 0.f};

    // prologue: stage kt0 -> buf0 (3 loads); drain
    stage_half256(Btile, K, &LDS[8192], t);
    stage_half128(Atile, lda, &LDS[0], t);
    asm volatile("s_waitcnt vmcnt(0)" ::: "memory");
    __builtin_amdgcn_s_barrier();
    asm volatile("" ::: "memory");

    int kt = 0;
    while (kt < NT) { GBODY(0) GBODY(1) }   // NT even (16 or 32)

    // epilogue: C/D layout col=lane&15, row=(lane>>4)*4+reg
    #pragma unroll
    for (int mi = 0; mi < 4; ++mi) {
        #pragma unroll
        for (int ni = 0; ni < 4; ++ni) {
            const int n = bn + wn * 64 + ni * 16 + fl;
            const float bv = bias[z * sBc + n];
            #pragma unroll
            for (int r = 0; r < 4; ++r) {
                const int m = bm + wm * 64 + mi * 16 + fh * 4 + r;
                float v = acc[mi][ni][r] + bv;
                if (MODE == 0) v = elu1(v);
                Obf[(size_t)z * sOc + (size_t)m * ldo + n] = __float2bfloat16(v);
            }
        }
    }
}

// ---------------------------------------------------------------------------
// 2-phase 128xBN kernel (round-2, proven) — for enc4 (N=64) / dec1 (K=64)
// ---------------------------------------------------------------------------
template<int BN, int MODE>
__global__ __launch_bounds__(256) void mfma_gemm(
    const __hip_bfloat16* __restrict__ A, size_t sAc, int lda, int K,
    const __hip_bfloat16* __restrict__ Wt, size_t sWc,
    const float* __restrict__ bias, int sBc,
    __hip_bfloat16* __restrict__ Obf, size_t sOc, int ldo,
    float* __restrict__ Of, int c0)
{
    constexpr int NI = BN / 32;
    __shared__ __align__(16) ushort_t As2[128 * 32];
    __shared__ __align__(16) ushort_t Bs2[BN * 32];

    const int t = threadIdx.x;
    const int wid = t >> 6, lane = t & 63;
    const int wm = wid >> 1, wn = wid & 1;
    const int z = blockIdx.z;
    const int bm = blockIdx.x * 128;
    const int bn = blockIdx.y * BN;

    const ushort_t* Ap = (const ushort_t*)A + (size_t)z * sAc;
    const ushort_t* Wp = (const ushort_t*)Wt + (size_t)z * sWc;

    const int srow = t >> 2;
    const int scol = (t & 3) << 3;
    const int fl = lane & 15, fh = lane >> 4;

    f32x4 zero4 = {0.f, 0.f, 0.f, 0.f};
    f32x4 acc[4][NI];
    #pragma unroll
    for (int mi = 0; mi < 4; ++mi)
        #pragma unroll
        for (int ni = 0; ni < NI; ++ni) acc[mi][ni] = zero4;

    for (int k0 = 0; k0 < K; k0 += 32) {
        #pragma unroll
        for (int i = 0; i < 2; ++i)
            gload_lds16(Ap + (size_t)(bm + i * 64 + srow) * lda + k0 + scol,
                        &As2[i * 2048 + wid * 512]);
        #pragma unroll
        for (int i = 0; i < BN / 64; ++i)
            gload_lds16(Wp + (size_t)(bn + i * 64 + srow) * K + k0 + scol,
                        &Bs2[i * 2048 + wid * 512]);
        __syncthreads();

        bf16x8 af[4], bfr[NI];
        #pragma unroll
        for (int mi = 0; mi < 4; ++mi)
            af[mi] = *(const bf16x8*)&As2[(wm * 64 + mi * 16 + fl) * 32 + fh * 8];
        #pragma unroll
        for (int ni = 0; ni < NI; ++ni)
            bfr[ni] = *(const bf16x8*)&Bs2[(wn * (BN / 2) + ni * 16 + fl) * 32 + fh * 8];
        #pragma unroll
        for (int mi = 0; mi < 4; ++mi)
            #pragma unroll
            for (int ni = 0; ni < NI; ++ni)
                acc[mi][ni] = __builtin_amdgcn_mfma_f32_16x16x32_bf16(
                    af[mi], bfr[ni], acc[mi][ni], 0, 0, 0);
        __syncthreads();
    }

    #pragma unroll
    for (int mi = 0; mi < 4; ++mi) {
        #pragma unroll
        for (int ni = 0; ni < NI; ++ni) {
            const int n = bn + wn * (BN / 2) + ni * 16 + fl;
            const float bv = bias[z * sBc + n];
            #pragma unroll
            for (int r = 0; r < 4; ++r) {
                const int m = bm + wm * 64 + mi * 16 + fh * 4 + r;
                float v = acc[mi][ni][r] + bv;
                if (MODE == 0) v = elu1(v);
                Obf[(size_t)z * sOc + (size_t)m * ldo + n] = __float2bfloat16(v);
                if (MODE == 1)
                    Of[(size_t)m * 512 + (size_t)(c0 + z) * 64 + n] = v;
            }
        }
    }
}

// fp32 [K][N] -> bf16 [N][K] (transpose + convert)
__global__ __launch_bounds__(256) void cvtT(
    const float* __restrict__ in, __hip_bfloat16* __restrict__ out,
    int K, int N, size_t sInC, size_t sOutC)
{
    __shared__ float tile[32][33];
    const float* ip = in + blockIdx.z * sInC;
    __hip_bfloat16* op = out + blockIdx.z * sOutC;
    const int n0 = blockIdx.x * 32, k0 = blockIdx.y * 32;
    const int x = threadIdx.x, y = threadIdx.y;
    #pragma unroll
    for (int j = 0; j < 4; ++j)
        tile[y + 8 * j][x] = ip[(size_t)(k0 + y + 8 * j) * N + n0 + x];
    __syncthreads();
    #pragma unroll
    for (int j = 0; j < 4; ++j)
        op[(size_t)(n0 + y + 8 * j) * K + k0 + x] = __float2bfloat16(tile[x][y + 8 * j]);
}

__global__ __launch_bounds__(256) void cvtx(
    const float* __restrict__ in, __hip_bfloat16* __restrict__ out, int n4)
{
    int i = blockIdx.x * 256 + threadIdx.x;
    if (i < n4) {
        float4 v = ((const float4*)in)[i];
        out[i * 4 + 0] = __float2bfloat16(v.x);
        out[i * 4 + 1] = __float2bfloat16(v.y);
        out[i * 4 + 2] = __float2bfloat16(v.z);
        out[i * 4 + 3] = __float2bfloat16(v.w);
    }
}

__global__ __launch_bounds__(256) void recon_group(
    const float* __restrict__ x, const __hip_bfloat16* __restrict__ xrec,
    const float* __restrict__ p, float* __restrict__ recon_x,
    float* __restrict__ err, int c0, int G)
{
    const int wid = threadIdx.x >> 6, lane = threadIdx.x & 63;
    const size_t b = (size_t)blockIdx.x * 4 + wid;
    const float4* xp = (const float4*)(x + b * 512);
    const float4 x0 = xp[lane * 2], x1 = xp[lane * 2 + 1];
    const float xv[8] = {x0.x, x0.y, x0.z, x0.w, x1.x, x1.y, x1.z, x1.w};
    float r[8] = {0.f, 0.f, 0.f, 0.f, 0.f, 0.f, 0.f, 0.f};

    for (int cc = 0; cc < G; ++cc) {
        const ushort_t* xr =
            (const ushort_t*)xrec + ((size_t)cc * 4096 + b) * 512 + lane * 8;
        bf16x8 v = *(const bf16x8*)xr;
        float pv = p[b * 8 + c0 + cc];
        float e = 0.f;
        #pragma unroll
        for (int j = 0; j < 8; ++j) {
            float f = (float)v[j];
            r[j] = fmaf(pv, f, r[j]);
            float d = xv[j] - f;
            e = fmaf(d, d, e);
        }
        #pragma unroll
        for (int off = 1; off < 64; off <<= 1) e += __shfl_xor(e, off, 64);
        if (lane == 0) err[b * 8 + c0 + cc] = e;
    }

    float4* op = (float4*)(recon_x + b * 512);
    float4 o0 = {r[0], r[1], r[2], r[3]}, o1 = {r[4], r[5], r[6], r[7]};
    if (c0) {
        float4 t0 = op[lane * 2], t1 = op[lane * 2 + 1];
        o0.x += t0.x; o0.y += t0.y; o0.z += t0.z; o0.w += t0.w;
        o1.x += t1.x; o1.y += t1.y; o1.z += t1.z; o1.w += t1.w;
    }
    op[lane * 2] = o0;
    op[lane * 2 + 1] = o1;
}

__global__ __launch_bounds__(256) void proj_sparsemax(
    const float* __restrict__ x, const float* __restrict__ Wp,
    const float* __restrict__ bp, float* __restrict__ p, int B, int D)
{
    int gw = (blockIdx.x * blockDim.x + threadIdx.x) >> 6;
    int lane = threadIdx.x & 63;
    if (gw >= B) return;
    const float* xr = x + (size_t)gw * D;
    float acc[8] = {0.f, 0.f, 0.f, 0.f, 0.f, 0.f, 0.f, 0.f};
    for (int d = lane; d < D; d += 64) {
        float xv = xr[d];
        #pragma unroll
        for (int c = 0; c < 8; ++c) acc[c] = fmaf(xv, Wp[d * 8 + c], acc[c]);
    }
    #pragma unroll
    for (int off = 32; off > 0; off >>= 1) {
        #pragma unroll
        for (int c = 0; c < 8; ++c) acc[c] += __shfl_xor(acc[c], off, 64);
    }
    if (lane == 0) {
        float s[8], zs[8];
        #pragma unroll
        for (int c = 0; c < 8; ++c) { s[c] = acc[c] + bp[c]; zs[c] = s[c]; }
        for (int i = 1; i < 8; ++i) {
            float v = zs[i];
            int j = i - 1;
            while (j >= 0 && zs[j] < v) { zs[j + 1] = zs[j]; --j; }
            zs[j + 1] = v;
        }
        float cs = 0.f, csel = 1.f;
        int kz = 1;
        for (int k = 1; k <= 8; ++k) {
            cs += zs[k - 1];
            if (1.f + (float)k * zs[k - 1] > cs) { kz = k; csel = cs; }
        }
        float tau = (csel - 1.f) / (float)kz;
        #pragma unroll
        for (int c = 0; c < 8; ++c) p[gw * 8 + c] = fmaxf(s[c] - tau, 0.f);
    }
}

__global__ __launch_bounds__(256) void losses_rows(
    const float* __restrict__ p, const float* __restrict__ err,
    float* __restrict__ acc, int B)
{
    __shared__ float s[10];
    int t = threadIdx.x;
    if (t < 10) s[t] = 0.f;
    __syncthreads();
    int b = blockIdx.x * 256 + t;
    if (b < B) {
        float pr[8], er[8];
        #pragma unroll
        for (int c = 0; c < 8; ++c) { pr[c] = p[b * 8 + c]; er[c] = err[b * 8 + c]; }
        float mn = er[0];
        #pragma unroll
        for (int c = 1; c < 8; ++c) mn = fminf(mn, er[c]);
        float q[8], se = 0.f;
        #pragma unroll
        for (int c = 0; c < 8; ++c) { q[c] = expf(mn - er[c]); se += q[c]; }
        float rl = 0.f, tl = 0.f;
        #pragma unroll
        for (int c = 0; c < 8; ++c) {
            rl = fmaf(pr[c], er[c], rl);
            tl = fmaf(q[c] / se, logf(pr[c] + 1e-8f), tl);
        }
        atomicAdd(&s[0], rl);
        atomicAdd(&s[1], tl);
        #pragma unroll
        for (int c = 0; c < 8; ++c) atomicAdd(&s[2 + c], pr[c]);
    }
    __syncthreads();
    if (t < 10) atomicAdd(&acc[t], s[t]);
}

__global__ __launch_bounds__(256) void mse_reduce(
    const float* __restrict__ recon_x, const float* __restrict__ x,
    float* __restrict__ acc, int n)
{
    float sm = 0.f;
    for (int i = blockIdx.x * 256 + threadIdx.x; i < n; i += gridDim.x * 256) {
        float d = recon_x[i] - x[i];
        sm = fmaf(d, d, sm);
    }
    __shared__ float sh;
    if (threadIdx.x == 0) sh = 0.f;
    __syncthreads();
    atomicAdd(&sh, sm);
    __syncthreads();
    if (threadIdx.x == 0) atomicAdd(&acc[10], sh);
}

__global__ void finalize_kernel(const float* __restrict__ acc,
                                float* __restrict__ scal, int B, int D)
{
    float invB = 1.f / (float)B;
    float recon = acc[0] * invB;
    float trans = -acc[1] * invB;
    float nondom = 0.f;
    for (int c = 0; c < 8; ++c) {
        float mp = acc[2 + c] * invB;
        float d = mp - 0.125f;
        nondom = fmaf(d, d, nondom);
    }
    float mse = acc[10] / ((float)B * (float)D);
    scal[0] = recon + trans + nondom;
    scal[1] = recon;
    scal[2] = nondom;
    scal[3] = trans;
    scal[4] = mse;
}

extern "C" void kernel_launch(void* const* d_in, const int* in_sizes, int n_in,
                              void* d_out, int out_size, void* d_ws, size_t ws_size,
                              hipStream_t stream)
{
    const int B = 4096, D = 512, L = 64, H = 1024, C = 8;

    const float* x   = (const float*)d_in[0];
    const float* We1 = (const float*)d_in[1];
    const float* be1 = (const float*)d_in[2];
    const float* We2 = (const float*)d_in[3];
    const float* be2 = (const float*)d_in[4];
    const float* We3 = (const float*)d_in[5];
    const float* be3 = (const float*)d_in[6];
    const float* We4 = (const float*)d_in[7];
    const float* be4 = (const float*)d_in[8];
    const float* Wd1 = (const float*)d_in[9];
    const float* bd1 = (const float*)d_in[10];
    const float* Wd2 = (const float*)d_in[11];
    const float* bd2 = (const float*)d_in[12];
    const float* Wd3 = (const float*)d_in[13];
    const float* bd3 = (const float*)d_in[14];
    const float* Wd4 = (const float*)d_in[15];
    const float* bd4 = (const float*)d_in[16];
    const float* Wp  = (const float*)d_in[17];
    const float* bp  = (const float*)d_in[18];

    float* out     = (float*)d_out;
    float* recon_x = out;                          // [B,D]
    float* zfp     = out + (size_t)B * D;          // [B,C,L]
    float* p       = zfp + (size_t)B * C * L;      // [B,C]
    float* scal    = p + (size_t)B * C;            // 5 scalars

    const size_t perG = ((size_t)H * H + 2ull * B * H + (size_t)B * D) * 2ull;
    const size_t fixedB = ((size_t)B * D + (size_t)C * B * L) * 2ull +
                          ((size_t)B * C + 16) * 4ull + 1024;
    int G = 8;
    while (G > 1 && fixedB + perG * (size_t)G > ws_size) G >>= 1;

    char* w = (char*)d_ws;
    __hip_bfloat16* xbf  = (__hip_bfloat16*)w; w += (size_t)B * D * 2;
    __hip_bfloat16* zbf  = (__hip_bfloat16*)w; w += (size_t)C * B * L * 2;
    __hip_bfloat16* wbuf = (__hip_bfloat16*)w; w += (size_t)G * H * H * 2;
    __hip_bfloat16* hA   = (__hip_bfloat16*)w; w += (size_t)G * B * H * 2;
    __hip_bfloat16* hB   = (__hip_bfloat16*)w; w += (size_t)G * B * H * 2;
    __hip_bfloat16* xrec = (__hip_bfloat16*)w; w += (size_t)G * B * D * 2;
    float* err = (float*)w; w += (size_t)B * C * 4;
    float* acc = (float*)w;

    hipMemsetAsync(acc, 0, 16 * sizeof(float), stream);

    cvtx<<<(B * D / 4 + 255) / 256, 256, 0, stream>>>(x, xbf, B * D / 4);
    proj_sparsemax<<<B / 4, 256, 0, stream>>>(x, Wp, bp, p, B, D);

    const dim3 cb(32, 8);
    const dim3 gSH(32, 4, 8);   // 128x256 tiles, N=1024
    const dim3 gSD(32, 2, 8);   // N=512

    for (int c0 = 0; c0 < C; c0 += G) {
        // enc1: [B,512] x [512,1024] -> hA (ELU), K=512 -> NT=16
        cvtT<<<dim3(H / 32, D / 32, G), cb, 0, stream>>>(
            We1 + (size_t)c0 * D * H, wbuf, D, H, (size_t)D * H, (size_t)D * H);
        gemmS<0, 16, 2><<<gSH, 512, 0, stream>>>(
            xbf, 0, D, wbuf, (size_t)D * H, be1 + (size_t)c0 * H, H,
            hA, (size_t)B * H, H);
        // enc2
        cvtT<<<dim3(H / 32, H / 32, G), cb, 0, stream>>>(
            We2 + (size_t)c0 * H * H, wbuf, H, H, (size_t)H * H, (size_t)H * H);
        gemmS<0, 32, 2><<<gSH, 512, 0, stream>>>(
            hA, (size_t)B * H, H, wbuf, (size_t)H * H, be2 + (size_t)c0 * H, H,
            hB, (size_t)B * H, H);
        // enc3
        cvtT<<<dim3(H / 32, H / 32, G), cb, 0, stream>>>(
            We3 + (size_t)c0 * H * H, wbuf, H, H, (size_t)H * H, (size_t)H * H);
        gemmS<0, 32, 2><<<gSH, 512, 0, stream>>>(
            hB, (size_t)B * H, H, wbuf, (size_t)H * H, be3 + (size_t)c0 * H, H,
            hA, (size_t)B * H, H);
        // enc4 -> z (fp32 to d_out, bf16 to ws) — 2-phase kernel (N=64)
        cvtT<<<dim3(L / 32, H / 32, G), cb, 0, stream>>>(
            We4 + (size_t)c0 * H * L, wbuf, H, L, (size_t)H * L, (size_t)H * L);
        mfma_gemm<64, 1><<<dim3(32, 1, G), 256, 0, stream>>>(
            hA, (size_t)B * H, H, H, wbuf, (size_t)H * L, be4 + (size_t)c0 * L, L,
            zbf + (size_t)c0 * B * L, (size_t)B * L, L, zfp, c0);
        // dec1: [B,64] x [64,1024] -> hB (ELU) — 2-phase kernel (K=64)
        cvtT<<<dim3(H / 32, L / 32, G), cb, 0, stream>>>(
            Wd1 + (size_t)c0 * L * H, wbuf, L, H, (size_t)L * H, (size_t)L * H);
        mfma_gemm<128, 0><<<dim3(32, 8, G), 256, 0, stream>>>(
            zbf + (size_t)c0 * B * L, (size_t)B * L, L, L, wbuf, (size_t)L * H,
            bd1 + (size_t)c0 * H, H, hB, (size_t)B * H, H, nullptr, 0);
        // dec2
        cvtT<<<dim3(H / 32, H / 32, G), cb, 0, stream>>>(
            Wd2 + (size_t)c0 * H * H, wbuf, H, H, (size_t)H * H, (size_t)H * H);
        gemmS<0, 32, 2><<<gSH, 512, 0, stream>>>(
            hB, (size_t)B * H, H, wbuf, (size_t)H * H, bd2 + (size_t)c0 * H, H,
            hA, (size_t)B * H, H);
        // dec3
        cvtT<<<dim3(H / 32, H / 32, G), cb, 0, stream>>>(
            Wd3 + (size_t)c0 * H * H, wbuf, H, H, (size_t)H * H, (size_t)H * H);
        gemmS<0, 32, 2><<<gSH, 512, 0, stream>>>(
            hA, (size_t)B * H, H, wbuf, (size_t)H * H, bd3 + (size_t)c0 * H, H,
            hB, (size_t)B * H, H);
        // dec4 -> x_recons (bf16), N=512
        cvtT<<<dim3(D / 32, H / 32, G), cb, 0, stream>>>(
            Wd4 + (size_t)c0 * H * D, wbuf, H, D, (size_t)H * D, (size_t)H * D);
        gemmS<2, 32, 1><<<gSD, 512, 0, stream>>>(
            hB, (size_t)B * H, H, wbuf, (size_t)H * D, bd4 + (size_t)c0 * D, D,
            xrec, (size_t)B * D, D);
        // fused recon_x accumulation + recon_errors
        recon_group<<<B / 4, 256, 0, stream>>>(x, xrec, p, recon_x, err, c0, G);
    }

    losses_rows<<<B / 256, 256, 0, stream>>>(p, err, acc, B);
    mse_reduce<<<1024, 256, 0, stream>>>(recon_x, x, acc, B * D);
    finalize_kernel<<<1, 1, 0, stream>>>(acc, scal, B, D);
}

// Round 13
// 590.929 us; speedup vs baseline: 8.6602x; 1.0135x over previous
//
#include <hip/hip_runtime.h>
#include <hip/hip_bf16.h>

typedef unsigned short ushort_t;
typedef __bf16 bf16x8 __attribute__((ext_vector_type(8)));
typedef float f32x4 __attribute__((ext_vector_type(4)));

__device__ __forceinline__ void gload_lds16(const void* g, void* l) {
    __builtin_amdgcn_global_load_lds(
        (const __attribute__((address_space(1))) void*)g,
        (__attribute__((address_space(3))) void*)l, 16, 0, 0);
}

__device__ __forceinline__ float elu1(float v) { return v > 0.f ? v : expm1f(v); }

// stage [256 rows][32 k] bf16 (16 KiB): 2 loads/thread (512 thr). LDS dest
// linear (t*16B), global source pre-swizzled: chunk bit1 ^= row bit3 (st_16x32).
__device__ __forceinline__ void stage_half256(const ushort_t* g, int ldg,
                                              ushort_t* lds, int t) {
    const int row = t >> 2;
    const int chunk = (t & 3) ^ ((t >> 4) & 2);
    const ushort_t* src = g + (size_t)row * ldg + chunk * 8;
    const int wo = (t >> 6) * 512;
    gload_lds16(src, lds + wo);
    gload_lds16(src + (size_t)128 * ldg, lds + 4096 + wo);
}
// stage [128 rows][32 k] (8 KiB): 1 load/thread
__device__ __forceinline__ void stage_half128(const ushort_t* g, int ldg,
                                              ushort_t* lds, int t) {
    const int row = t >> 2;
    const int chunk = (t & 3) ^ ((t >> 4) & 2);
    gload_lds16(g + (size_t)row * ldg + chunk * 8, lds + (t >> 6) * 512);
}

// ---------------------------------------------------------------------------
// 128x256 MFMA GEMM, BK=32, 8 waves (2M x 4N), 64x64/wave (acc[4][4]).
// R11 champion: ONE barrier/kt, compiler lgkm waits, counted vmcnt(3),
// 3-deep rotation w/ STATIC buffer offsets (unroll-by-3), bn-low L2 ordering.
// LDS (ushorts): A @ 0,4096,8192 ; B @ 12288,20480,28672.
// ---------------------------------------------------------------------------
#define LDA(J_, MI_) (*(const bf16x8*)(LDSc + vA + ((J_) * 8192 + (MI_) * 1024)))
#define LDB(J_, NI_) (*(const bf16x8*)(LDSc + vB + ((J_) * 16384 + (NI_) * 1024)))

#define GBODY(J_)                                                              \
  {                                                                            \
    bf16x8 a0 = LDA(J_, 0), a1 = LDA(J_, 1), a2 = LDA(J_, 2), a3 = LDA(J_, 3); \
    bf16x8 b0 = LDB(J_, 0), b1 = LDB(J_, 1), b2 = LDB(J_, 2), b3 = LDB(J_, 3); \
    if (kt + 2 < NT) {                                                         \
      constexpr int W_ = ((J_) + 2) % 3;                                       \
      stage_half256(Btile + (size_t)(kt + 2) * 32, K, &LDS[12288 + W_ * 8192], t); \
      stage_half128(Atile + (size_t)(kt + 2) * 32, lda, &LDS[W_ * 4096], t);   \
    }                                                                          \
    __builtin_amdgcn_s_setprio(1);                                             \
    acc[0][0] = __builtin_amdgcn_mfma_f32_16x16x32_bf16(a0, b0, acc[0][0], 0, 0, 0); \
    acc[0][1] = __builtin_amdgcn_mfma_f32_16x16x32_bf16(a0, b1, acc[0][1], 0, 0, 0); \
    acc[0][2] = __builtin_amdgcn_mfma_f32_16x16x32_bf16(a0, b2, acc[0][2], 0, 0, 0); \
    acc[0][3] = __builtin_amdgcn_mfma_f32_16x16x32_bf16(a0, b3, acc[0][3], 0, 0, 0); \
    acc[1][0] = __builtin_amdgcn_mfma_f32_16x16x32_bf16(a1, b0, acc[1][0], 0, 0, 0); \
    acc[1][1] = __builtin_amdgcn_mfma_f32_16x16x32_bf16(a1, b1, acc[1][1], 0, 0, 0); \
    acc[1][2] = __builtin_amdgcn_mfma_f32_16x16x32_bf16(a1, b2, acc[1][2], 0, 0, 0); \
    acc[1][3] = __builtin_amdgcn_mfma_f32_16x16x32_bf16(a1, b3, acc[1][3], 0, 0, 0); \
    acc[2][0] = __builtin_amdgcn_mfma_f32_16x16x32_bf16(a2, b0, acc[2][0], 0, 0, 0); \
    acc[2][1] = __builtin_amdgcn_mfma_f32_16x16x32_bf16(a2, b1, acc[2][1], 0, 0, 0); \
    acc[2][2] = __builtin_amdgcn_mfma_f32_16x16x32_bf16(a2, b2, acc[2][2], 0, 0, 0); \
    acc[2][3] = __builtin_amdgcn_mfma_f32_16x16x32_bf16(a2, b3, acc[2][3], 0, 0, 0); \
    acc[3][0] = __builtin_amdgcn_mfma_f32_16x16x32_bf16(a3, b0, acc[3][0], 0, 0, 0); \
    acc[3][1] = __builtin_amdgcn_mfma_f32_16x16x32_bf16(a3, b1, acc[3][1], 0, 0, 0); \
    acc[3][2] = __builtin_amdgcn_mfma_f32_16x16x32_bf16(a3, b2, acc[3][2], 0, 0, 0); \
    acc[3][3] = __builtin_amdgcn_mfma_f32_16x16x32_bf16(a3, b3, acc[3][3], 0, 0, 0); \
    __builtin_amdgcn_s_setprio(0);                                             \
    if (kt < NT - 2) asm volatile("s_waitcnt vmcnt(3)" ::: "memory");          \
    else             asm volatile("s_waitcnt vmcnt(0)" ::: "memory");          \
    __builtin_amdgcn_s_barrier();                                              \
    asm volatile("" ::: "memory");                                             \
    ++kt;                                                                      \
  }

template<int MODE, int NT, int LNB>
__global__ __launch_bounds__(512, 4) void gemmS(
    const __hip_bfloat16* __restrict__ A, size_t sAc, int lda,
    const __hip_bfloat16* __restrict__ Wt, size_t sWc,
    const float* __restrict__ bias, int sBc,
    __hip_bfloat16* __restrict__ Obf, size_t sOc, int ldo)
{
    constexpr int K = NT * 32;
    __shared__ __align__(16) ushort_t LDS[36864];   // 72 KiB -> 2 blocks/CU

    const int t = threadIdx.x;
    const int wid = t >> 6, lane = t & 63;
    const int wm = wid >> 2, wn = wid & 3;
    const int fl = lane & 15, fh = lane >> 4;

    // bijective XCD swizzle: orig%8 -> XCD gets a contiguous chunk (= 1 chart).
    // bn in LOW bits: bn-siblings of each bm co-resident -> B-panel L2-resident,
    // each A block-row fetched once (R11: FETCH 130->56 MB).
    const int orig = blockIdx.x + 32 * blockIdx.y + (32 << LNB) * blockIdx.z;
    const int q = (32 << LNB);                 // nwg/8 (gridDim.z == 8)
    const int wg = (orig & 7) * q + (orig >> 3);
    const int z = wg >> (5 + LNB);
    const int inner = wg & ((32 << LNB) - 1);
    const int bm = (inner >> LNB) * 128;
    const int bn = (inner & ((1 << LNB) - 1)) * 256;

    const ushort_t* Atile = (const ushort_t*)A + (size_t)z * sAc + (size_t)bm * lda;
    const ushort_t* Btile = (const ushort_t*)Wt + (size_t)z * sWc + (size_t)bn * K;

    // per-lane LDS read addresses; swizzle reduced to lane-only form:
    // (r>>2)&2 == (fl>>2)&2 for r = 64*w + 16*frag + fl (frag-independent).
    const char* LDSc = (const char*)&LDS[0];
    const unsigned lanepart = fl * 64 + ((fh ^ ((fl >> 2) & 2)) << 4);
    const unsigned vA = wm * 4096 + lanepart;
    const unsigned vB = 24576 + wn * 4096 + lanepart;

    f32x4 acc[4][4];
    #pragma unroll
    for (int i = 0; i < 4; ++i)
        #pragma unroll
        for (int j = 0; j < 4; ++j) acc[i][j] = (f32x4){0.f, 0.f, 0.f, 0.f};

    // prologue: stage kt0 -> buf0, kt1 -> buf1 (6 loads); wait kt0's 3
    stage_half256(Btile, K, &LDS[12288], t);
    stage_half128(Atile, lda, &LDS[0], t);
    stage_half256(Btile + 32, K, &LDS[12288 + 8192], t);
    stage_half128(Atile + 32, lda, &LDS[4096], t);
    asm volatile("s_waitcnt vmcnt(3)" ::: "memory");
    __builtin_amdgcn_s_barrier();
    asm volatile("" ::: "memory");

    int kt = 0;
    while (kt + 3 <= NT) { GBODY(0) GBODY(1) GBODY(2) }
    if constexpr (NT % 3 >= 1) { GBODY(0) }
    if constexpr (NT % 3 >= 2) { GBODY(1) }

    // epilogue: C/D layout col=lane&15, row=(lane>>4)*4+reg
    #pragma unroll
    for (int mi = 0; mi < 4; ++mi) {
        #pragma unroll
        for (int ni = 0; ni < 4; ++ni) {
            const int n = bn + wn * 64 + ni * 16 + fl;
            const float bv = bias[z * sBc + n];
            #pragma unroll
            for (int r = 0; r < 4; ++r) {
                const int m = bm + wm * 64 + mi * 16 + fh * 4 + r;
                float v = acc[mi][ni][r] + bv;
                if (MODE == 0) v = elu1(v);
                Obf[(size_t)z * sOc + (size_t)m * ldo + n] = __float2bfloat16(v);
            }
        }
    }
}

// ---------------------------------------------------------------------------
// 2-phase 128xBN kernel (round-2, proven) — kept for enc4 (N=64, MODE 1)
// ---------------------------------------------------------------------------
template<int BN, int MODE>
__global__ __launch_bounds__(256) void mfma_gemm(
    const __hip_bfloat16* __restrict__ A, size_t sAc, int lda, int K,
    const __hip_bfloat16* __restrict__ Wt, size_t sWc,
    const float* __restrict__ bias, int sBc,
    __hip_bfloat16* __restrict__ Obf, size_t sOc, int ldo,
    float* __restrict__ Of, int c0)
{
    constexpr int NI = BN / 32;
    __shared__ __align__(16) ushort_t As2[128 * 32];
    __shared__ __align__(16) ushort_t Bs2[BN * 32];

    const int t = threadIdx.x;
    const int wid = t >> 6, lane = t & 63;
    const int wm = wid >> 1, wn = wid & 1;
    const int z = blockIdx.z;
    const int bm = blockIdx.x * 128;
    const int bn = blockIdx.y * BN;

    const ushort_t* Ap = (const ushort_t*)A + (size_t)z * sAc;
    const ushort_t* Wp = (const ushort_t*)Wt + (size_t)z * sWc;

    const int srow = t >> 2;
    const int scol = (t & 3) << 3;
    const int fl = lane & 15, fh = lane >> 4;

    f32x4 zero4 = {0.f, 0.f, 0.f, 0.f};
    f32x4 acc[4][NI];
    #pragma unroll
    for (int mi = 0; mi < 4; ++mi)
        #pragma unroll
        for (int ni = 0; ni < NI; ++ni) acc[mi][ni] = zero4;

    for (int k0 = 0; k0 < K; k0 += 32) {
        #pragma unroll
        for (int i = 0; i < 2; ++i)
            gload_lds16(Ap + (size_t)(bm + i * 64 + srow) * lda + k0 + scol,
                        &As2[i * 2048 + wid * 512]);
        #pragma unroll
        for (int i = 0; i < BN / 64; ++i)
            gload_lds16(Wp + (size_t)(bn + i * 64 + srow) * K + k0 + scol,
                        &Bs2[i * 2048 + wid * 512]);
        __syncthreads();

        bf16x8 af[4], bfr[NI];
        #pragma unroll
        for (int mi = 0; mi < 4; ++mi)
            af[mi] = *(const bf16x8*)&As2[(wm * 64 + mi * 16 + fl) * 32 + fh * 8];
        #pragma unroll
        for (int ni = 0; ni < NI; ++ni)
            bfr[ni] = *(const bf16x8*)&Bs2[(wn * (BN / 2) + ni * 16 + fl) * 32 + fh * 8];
        #pragma unroll
        for (int mi = 0; mi < 4; ++mi)
            #pragma unroll
            for (int ni = 0; ni < NI; ++ni)
                acc[mi][ni] = __builtin_amdgcn_mfma_f32_16x16x32_bf16(
                    af[mi], bfr[ni], acc[mi][ni], 0, 0, 0);
        __syncthreads();
    }

    #pragma unroll
    for (int mi = 0; mi < 4; ++mi) {
        #pragma unroll
        for (int ni = 0; ni < NI; ++ni) {
            const int n = bn + wn * (BN / 2) + ni * 16 + fl;
            const float bv = bias[z * sBc + n];
            #pragma unroll
            for (int r = 0; r < 4; ++r) {
                const int m = bm + wm * 64 + mi * 16 + fh * 4 + r;
                float v = acc[mi][ni][r] + bv;
                if (MODE == 0) v = elu1(v);
                Obf[(size_t)z * sOc + (size_t)m * ldo + n] = __float2bfloat16(v);
                if (MODE == 1)
                    Of[(size_t)m * 512 + (size_t)(c0 + z) * 64 + n] = v;
            }
        }
    }
}

// fp32 [K][N] -> bf16 [N][K] (transpose + convert)
__global__ __launch_bounds__(256) void cvtT(
    const float* __restrict__ in, __hip_bfloat16* __restrict__ out,
    int K, int N, size_t sInC, size_t sOutC)
{
    __shared__ float tile[32][33];
    const float* ip = in + blockIdx.z * sInC;
    __hip_bfloat16* op = out + blockIdx.z * sOutC;
    const int n0 = blockIdx.x * 32, k0 = blockIdx.y * 32;
    const int x = threadIdx.x, y = threadIdx.y;
    #pragma unroll
    for (int j = 0; j < 4; ++j)
        tile[y + 8 * j][x] = ip[(size_t)(k0 + y + 8 * j) * N + n0 + x];
    __syncthreads();
    #pragma unroll
    for (int j = 0; j < 4; ++j)
        op[(size_t)(n0 + y + 8 * j) * K + k0 + x] = __float2bfloat16(tile[x][y + 8 * j]);
}

__global__ __launch_bounds__(256) void recon_group(
    const float* __restrict__ x, const __hip_bfloat16* __restrict__ xrec,
    const float* __restrict__ p, float* __restrict__ recon_x,
    float* __restrict__ err, int c0, int G)
{
    const int wid = threadIdx.x >> 6, lane = threadIdx.x & 63;
    const size_t b = (size_t)blockIdx.x * 4 + wid;
    const float4* xp = (const float4*)(x + b * 512);
    const float4 x0 = xp[lane * 2], x1 = xp[lane * 2 + 1];
    const float xv[8] = {x0.x, x0.y, x0.z, x0.w, x1.x, x1.y, x1.z, x1.w};
    float r[8] = {0.f, 0.f, 0.f, 0.f, 0.f, 0.f, 0.f, 0.f};

    for (int cc = 0; cc < G; ++cc) {
        const ushort_t* xr =
            (const ushort_t*)xrec + ((size_t)cc * 4096 + b) * 512 + lane * 8;
        bf16x8 v = *(const bf16x8*)xr;
        float pv = p[b * 8 + c0 + cc];
        float e = 0.f;
        #pragma unroll
        for (int j = 0; j < 8; ++j) {
            float f = (float)v[j];
            r[j] = fmaf(pv, f, r[j]);
            float d = xv[j] - f;
            e = fmaf(d, d, e);
        }
        #pragma unroll
        for (int off = 1; off < 64; off <<= 1) e += __shfl_xor(e, off, 64);
        if (lane == 0) err[b * 8 + c0 + cc] = e;
    }

    float4* op = (float4*)(recon_x + b * 512);
    float4 o0 = {r[0], r[1], r[2], r[3]}, o1 = {r[4], r[5], r[6], r[7]};
    if (c0) {
        float4 t0 = op[lane * 2], t1 = op[lane * 2 + 1];
        o0.x += t0.x; o0.y += t0.y; o0.z += t0.z; o0.w += t0.w;
        o1.x += t1.x; o1.y += t1.y; o1.z += t1.z; o1.w += t1.w;
    }
    op[lane * 2] = o0;
    op[lane * 2 + 1] = o1;
}

// proj + sparsemax + inline x->bf16 conversion (replaces cvtx launch)
__global__ __launch_bounds__(256) void proj_sparsemax(
    const float* __restrict__ x, const float* __restrict__ Wp,
    const float* __restrict__ bp, float* __restrict__ p,
    __hip_bfloat16* __restrict__ xbf, int B, int D)
{
    int gw = (blockIdx.x * blockDim.x + threadIdx.x) >> 6;
    int lane = threadIdx.x & 63;
    if (gw >= B) return;
    const float* xr = x + (size_t)gw * D;
    __hip_bfloat16* xo = xbf + (size_t)gw * D;
    float acc[8] = {0.f, 0.f, 0.f, 0.f, 0.f, 0.f, 0.f, 0.f};
    for (int d = lane; d < D; d += 64) {
        float xv = xr[d];
        xo[d] = __float2bfloat16(xv);
        #pragma unroll
        for (int c = 0; c < 8; ++c) acc[c] = fmaf(xv, Wp[d * 8 + c], acc[c]);
    }
    #pragma unroll
    for (int off = 32; off > 0; off >>= 1) {
        #pragma unroll
        for (int c = 0; c < 8; ++c) acc[c] += __shfl_xor(acc[c], off, 64);
    }
    if (lane == 0) {
        float s[8], zs[8];
        #pragma unroll
        for (int c = 0; c < 8; ++c) { s[c] = acc[c] + bp[c]; zs[c] = s[c]; }
        for (int i = 1; i < 8; ++i) {
            float v = zs[i];
            int j = i - 1;
            while (j >= 0 && zs[j] < v) { zs[j + 1] = zs[j]; --j; }
            zs[j + 1] = v;
        }
        float cs = 0.f, csel = 1.f;
        int kz = 1;
        for (int k = 1; k <= 8; ++k) {
            cs += zs[k - 1];
            if (1.f + (float)k * zs[k - 1] > cs) { kz = k; csel = cs; }
        }
        float tau = (csel - 1.f) / (float)kz;
        #pragma unroll
        for (int c = 0; c < 8; ++c) p[gw * 8 + c] = fmaxf(s[c] - tau, 0.f);
    }
}

// losses + mse + finalize in ONE launch (last-block ticket pattern).
// acc slots: 0=sum p*err, 1=sum q*log(p), 2..9=sum p[:,c], 10=mse sum,
// 12=ticket (uint). Zeroed by memset before launch.
__global__ __launch_bounds__(256) void tail_reduce(
    const float* __restrict__ p, const float* __restrict__ err,
    const float* __restrict__ recon_x, const float* __restrict__ x,
    float* __restrict__ acc, float* __restrict__ scal,
    int B, int D, int nblocks)
{
    __shared__ float s[11];
    const int t = threadIdx.x;
    if (t < 11) s[t] = 0.f;
    __syncthreads();

    // losses part (rows live in blocks 0..B/256-1)
    int b = blockIdx.x * 256 + t;
    if (b < B) {
        float pr[8], er[8];
        #pragma unroll
        for (int c = 0; c < 8; ++c) { pr[c] = p[b * 8 + c]; er[c] = err[b * 8 + c]; }
        float mn = er[0];
        #pragma unroll
        for (int c = 1; c < 8; ++c) mn = fminf(mn, er[c]);
        float q[8], se = 0.f;
        #pragma unroll
        for (int c = 0; c < 8; ++c) { q[c] = expf(mn - er[c]); se += q[c]; }
        float rl = 0.f, tl = 0.f;
        #pragma unroll
        for (int c = 0; c < 8; ++c) {
            rl = fmaf(pr[c], er[c], rl);
            tl = fmaf(q[c] / se, logf(pr[c] + 1e-8f), tl);
        }
        atomicAdd(&s[0], rl);
        atomicAdd(&s[1], tl);
        #pragma unroll
        for (int c = 0; c < 8; ++c) atomicAdd(&s[2 + c], pr[c]);
    }

    // mse part (grid-stride)
    float sm = 0.f;
    const int n = B * D;
    for (int i = blockIdx.x * 256 + t; i < n; i += nblocks * 256) {
        float d = recon_x[i] - x[i];
        sm = fmaf(d, d, sm);
    }
    atomicAdd(&s[10], sm);
    __syncthreads();

    if (t < 11) {
        atomicAdd(&acc[t], s[t]);
        __threadfence();
    }
    __syncthreads();

    if (t == 0) {
        unsigned tk = atomicAdd((unsigned*)&acc[12], 1u);
        if (tk == (unsigned)(nblocks - 1)) {
            float invB = 1.f / (float)B;
            float recon = acc[0] * invB;
            float trans = -acc[1] * invB;
            float nondom = 0.f;
            for (int c = 0; c < 8; ++c) {
                float mp = acc[2 + c] * invB;
                float d = mp - 0.125f;
                nondom = fmaf(d, d, nondom);
            }
            float mse = acc[10] / ((float)B * (float)D);
            scal[0] = recon + trans + nondom;
            scal[1] = recon;
            scal[2] = nondom;
            scal[3] = trans;
            scal[4] = mse;
        }
    }
}

extern "C" void kernel_launch(void* const* d_in, const int* in_sizes, int n_in,
                              void* d_out, int out_size, void* d_ws, size_t ws_size,
                              hipStream_t stream)
{
    const int B = 4096, D = 512, L = 64, H = 1024, C = 8;

    const float* x   = (const float*)d_in[0];
    const float* We1 = (const float*)d_in[1];
    const float* be1 = (const float*)d_in[2];
    const float* We2 = (const float*)d_in[3];
    const float* be2 = (const float*)d_in[4];
    const float* We3 = (const float*)d_in[5];
    const float* be3 = (const float*)d_in[6];
    const float* We4 = (const float*)d_in[7];
    const float* be4 = (const float*)d_in[8];
    const float* Wd1 = (const float*)d_in[9];
    const float* bd1 = (const float*)d_in[10];
    const float* Wd2 = (const float*)d_in[11];
    const float* bd2 = (const float*)d_in[12];
    const float* Wd3 = (const float*)d_in[13];
    const float* bd3 = (const float*)d_in[14];
    const float* Wd4 = (const float*)d_in[15];
    const float* bd4 = (const float*)d_in[16];
    const float* Wp  = (const float*)d_in[17];
    const float* bp  = (const float*)d_in[18];

    float* out     = (float*)d_out;
    float* recon_x = out;                          // [B,D]
    float* zfp     = out + (size_t)B * D;          // [B,C,L]
    float* p       = zfp + (size_t)B * C * L;      // [B,C]
    float* scal    = p + (size_t)B * C;            // 5 scalars

    const size_t perG = ((size_t)H * H + 2ull * B * H + (size_t)B * D) * 2ull;
    const size_t fixedB = ((size_t)B * D + (size_t)C * B * L) * 2ull +
                          ((size_t)B * C + 16) * 4ull + 1024;
    int G = 8;
    while (G > 1 && fixedB + perG * (size_t)G > ws_size) G >>= 1;

    char* w = (char*)d_ws;
    __hip_bfloat16* xbf  = (__hip_bfloat16*)w; w += (size_t)B * D * 2;
    __hip_bfloat16* zbf  = (__hip_bfloat16*)w; w += (size_t)C * B * L * 2;
    __hip_bfloat16* wbuf = (__hip_bfloat16*)w; w += (size_t)G * H * H * 2;
    __hip_bfloat16* hA   = (__hip_bfloat16*)w; w += (size_t)G * B * H * 2;
    __hip_bfloat16* hB   = (__hip_bfloat16*)w; w += (size_t)G * B * H * 2;
    __hip_bfloat16* xrec = (__hip_bfloat16*)w; w += (size_t)G * B * D * 2;
    float* err = (float*)w; w += (size_t)B * C * 4;
    float* acc = (float*)w;

    hipMemsetAsync(acc, 0, 16 * sizeof(float), stream);

    proj_sparsemax<<<B / 4, 256, 0, stream>>>(x, Wp, bp, p, xbf, B, D);

    const dim3 cb(32, 8);
    const dim3 gSH(32, 4, 8);   // 128x256 tiles, N=1024
    const dim3 gSD(32, 2, 8);   // N=512

    for (int c0 = 0; c0 < C; c0 += G) {
        // enc1: [B,512] x [512,1024] -> hA (ELU), K=512 -> NT=16
        cvtT<<<dim3(H / 32, D / 32, G), cb, 0, stream>>>(
            We1 + (size_t)c0 * D * H, wbuf, D, H, (size_t)D * H, (size_t)D * H);
        gemmS<0, 16, 2><<<gSH, 512, 0, stream>>>(
            xbf, 0, D, wbuf, (size_t)D * H, be1 + (size_t)c0 * H, H,
            hA, (size_t)B * H, H);
        // enc2
        cvtT<<<dim3(H / 32, H / 32, G), cb, 0, stream>>>(
            We2 + (size_t)c0 * H * H, wbuf, H, H, (size_t)H * H, (size_t)H * H);
        gemmS<0, 32, 2><<<gSH, 512, 0, stream>>>(
            hA, (size_t)B * H, H, wbuf, (size_t)H * H, be2 + (size_t)c0 * H, H,
            hB, (size_t)B * H, H);
        // enc3
        cvtT<<<dim3(H / 32, H / 32, G), cb, 0, stream>>>(
            We3 + (size_t)c0 * H * H, wbuf, H, H, (size_t)H * H, (size_t)H * H);
        gemmS<0, 32, 2><<<gSH, 512, 0, stream>>>(
            hB, (size_t)B * H, H, wbuf, (size_t)H * H, be3 + (size_t)c0 * H, H,
            hA, (size_t)B * H, H);
        // enc4 -> z (fp32 to d_out, bf16 to ws) — 2-phase kernel (N=64)
        cvtT<<<dim3(L / 32, H / 32, G), cb, 0, stream>>>(
            We4 + (size_t)c0 * H * L, wbuf, H, L, (size_t)H * L, (size_t)H * L);
        mfma_gemm<64, 1><<<dim3(32, 1, G), 256, 0, stream>>>(
            hA, (size_t)B * H, H, H, wbuf, (size_t)H * L, be4 + (size_t)c0 * L, L,
            zbf + (size_t)c0 * B * L, (size_t)B * L, L, zfp, c0);
        // dec1: [B,64] x [64,1024] -> hB (ELU), K=64 -> gemmS NT=2
        cvtT<<<dim3(H / 32, L / 32, G), cb, 0, stream>>>(
            Wd1 + (size_t)c0 * L * H, wbuf, L, H, (size_t)L * H, (size_t)L * H);
        gemmS<0, 2, 2><<<gSH, 512, 0, stream>>>(
            zbf + (size_t)c0 * B * L, (size_t)B * L, L, wbuf, (size_t)L * H,
            bd1 + (size_t)c0 * H, H, hB, (size_t)B * H, H);
        // dec2
        cvtT<<<dim3(H / 32, H / 32, G), cb, 0, stream>>>(
            Wd2 + (size_t)c0 * H * H, wbuf, H, H, (size_t)H * H, (size_t)H * H);
        gemmS<0, 32, 2><<<gSH, 512, 0, stream>>>(
            hB, (size_t)B * H, H, wbuf, (size_t)H * H, bd2 + (size_t)c0 * H, H,
            hA, (size_t)B * H, H);
        // dec3
        cvtT<<<dim3(H / 32, H / 32, G), cb, 0, stream>>>(
            Wd3 + (size_t)c0 * H * H, wbuf, H, H, (size_t)H * H, (size_t)H * H);
        gemmS<0, 32, 2><<<gSH, 512, 0, stream>>>(
            hA, (size_t)B * H, H, wbuf, (size_t)H * H, bd3 + (size_t)c0 * H, H,
            hB, (size_t)B * H, H);
        // dec4 -> x_recons (bf16), N=512
        cvtT<<<dim3(D / 32, H / 32, G), cb, 0, stream>>>(
            Wd4 + (size_t)c0 * H * D, wbuf, H, D, (size_t)H * D, (size_t)H * D);
        gemmS<2, 32, 1><<<gSD, 512, 0, stream>>>(
            hB, (size_t)B * H, H, wbuf, (size_t)H * D, bd4 + (size_t)c0 * D, D,
            xrec, (size_t)B * D, D);
        // fused recon_x accumulation + recon_errors
        recon_group<<<B / 4, 256, 0, stream>>>(x, xrec, p, recon_x, err, c0, G);
    }

    tail_reduce<<<1024, 256, 0, stream>>>(p, err, recon_x, x, acc, scal, B, D, 1024);
}

// Round 14
// 579.386 us; speedup vs baseline: 8.8327x; 1.0199x over previous
//
#include <hip/hip_runtime.h>
#include <hip/hip_bf16.h>

typedef unsigned short ushort_t;
typedef __bf16 bf16x8 __attribute__((ext_vector_type(8)));
typedef float f32x4 __attribute__((ext_vector_type(4)));

__device__ __forceinline__ void gload_lds16(const void* g, void* l) {
    __builtin_amdgcn_global_load_lds(
        (const __attribute__((address_space(1))) void*)g,
        (__attribute__((address_space(3))) void*)l, 16, 0, 0);
}

__device__ __forceinline__ float elu1(float v) { return v > 0.f ? v : expm1f(v); }

// stage [256 rows][32 k] bf16 (16 KiB): 2 loads/thread (512 thr). LDS dest
// linear (t*16B), global source pre-swizzled: chunk bit1 ^= row bit3 (st_16x32).
__device__ __forceinline__ void stage_half256(const ushort_t* g, int ldg,
                                              ushort_t* lds, int t) {
    const int row = t >> 2;
    const int chunk = (t & 3) ^ ((t >> 4) & 2);
    const ushort_t* src = g + (size_t)row * ldg + chunk * 8;
    const int wo = (t >> 6) * 512;
    gload_lds16(src, lds + wo);
    gload_lds16(src + (size_t)128 * ldg, lds + 4096 + wo);
}
// stage [128 rows][32 k] (8 KiB): 1 load/thread
__device__ __forceinline__ void stage_half128(const ushort_t* g, int ldg,
                                              ushort_t* lds, int t) {
    const int row = t >> 2;
    const int chunk = (t & 3) ^ ((t >> 4) & 2);
    gload_lds16(g + (size_t)row * ldg + chunk * 8, lds + (t >> 6) * 512);
}

// ---------------------------------------------------------------------------
// 128x256 MFMA GEMM, BK=32, 8 waves (2M x 4N), 64x64/wave (acc[4][4]).
// R11 champion: ONE barrier/kt, compiler lgkm waits, counted vmcnt(3),
// 3-deep rotation w/ STATIC buffer offsets (unroll-by-3), bn-low L2 ordering.
// LDS (ushorts): A @ 0,4096,8192 ; B @ 12288,20480,28672.
// ---------------------------------------------------------------------------
#define LDA(J_, MI_) (*(const bf16x8*)(LDSc + vA + ((J_) * 8192 + (MI_) * 1024)))
#define LDB(J_, NI_) (*(const bf16x8*)(LDSc + vB + ((J_) * 16384 + (NI_) * 1024)))

#define GBODY(J_)                                                              \
  {                                                                            \
    bf16x8 a0 = LDA(J_, 0), a1 = LDA(J_, 1), a2 = LDA(J_, 2), a3 = LDA(J_, 3); \
    bf16x8 b0 = LDB(J_, 0), b1 = LDB(J_, 1), b2 = LDB(J_, 2), b3 = LDB(J_, 3); \
    if (kt + 2 < NT) {                                                         \
      constexpr int W_ = ((J_) + 2) % 3;                                       \
      stage_half256(Btile + (size_t)(kt + 2) * 32, K, &LDS[12288 + W_ * 8192], t); \
      stage_half128(Atile + (size_t)(kt + 2) * 32, lda, &LDS[W_ * 4096], t);   \
    }                                                                          \
    __builtin_amdgcn_s_setprio(1);                                             \
    acc[0][0] = __builtin_amdgcn_mfma_f32_16x16x32_bf16(a0, b0, acc[0][0], 0, 0, 0); \
    acc[0][1] = __builtin_amdgcn_mfma_f32_16x16x32_bf16(a0, b1, acc[0][1], 0, 0, 0); \
    acc[0][2] = __builtin_amdgcn_mfma_f32_16x16x32_bf16(a0, b2, acc[0][2], 0, 0, 0); \
    acc[0][3] = __builtin_amdgcn_mfma_f32_16x16x32_bf16(a0, b3, acc[0][3], 0, 0, 0); \
    acc[1][0] = __builtin_amdgcn_mfma_f32_16x16x32_bf16(a1, b0, acc[1][0], 0, 0, 0); \
    acc[1][1] = __builtin_amdgcn_mfma_f32_16x16x32_bf16(a1, b1, acc[1][1], 0, 0, 0); \
    acc[1][2] = __builtin_amdgcn_mfma_f32_16x16x32_bf16(a1, b2, acc[1][2], 0, 0, 0); \
    acc[1][3] = __builtin_amdgcn_mfma_f32_16x16x32_bf16(a1, b3, acc[1][3], 0, 0, 0); \
    acc[2][0] = __builtin_amdgcn_mfma_f32_16x16x32_bf16(a2, b0, acc[2][0], 0, 0, 0); \
    acc[2][1] = __builtin_amdgcn_mfma_f32_16x16x32_bf16(a2, b1, acc[2][1], 0, 0, 0); \
    acc[2][2] = __builtin_amdgcn_mfma_f32_16x16x32_bf16(a2, b2, acc[2][2], 0, 0, 0); \
    acc[2][3] = __builtin_amdgcn_mfma_f32_16x16x32_bf16(a2, b3, acc[2][3], 0, 0, 0); \
    acc[3][0] = __builtin_amdgcn_mfma_f32_16x16x32_bf16(a3, b0, acc[3][0], 0, 0, 0); \
    acc[3][1] = __builtin_amdgcn_mfma_f32_16x16x32_bf16(a3, b1, acc[3][1], 0, 0, 0); \
    acc[3][2] = __builtin_amdgcn_mfma_f32_16x16x32_bf16(a3, b2, acc[3][2], 0, 0, 0); \
    acc[3][3] = __builtin_amdgcn_mfma_f32_16x16x32_bf16(a3, b3, acc[3][3], 0, 0, 0); \
    __builtin_amdgcn_s_setprio(0);                                             \
    if (kt < NT - 2) asm volatile("s_waitcnt vmcnt(3)" ::: "memory");          \
    else             asm volatile("s_waitcnt vmcnt(0)" ::: "memory");          \
    __builtin_amdgcn_s_barrier();                                              \
    asm volatile("" ::: "memory");                                             \
    ++kt;                                                                      \
  }

template<int MODE, int NT, int LNB>
__global__ __launch_bounds__(512, 4) void gemmS(
    const __hip_bfloat16* __restrict__ A, size_t sAc, int lda,
    const __hip_bfloat16* __restrict__ Wt, size_t sWc,
    const float* __restrict__ bias, int sBc,
    __hip_bfloat16* __restrict__ Obf, size_t sOc, int ldo)
{
    constexpr int K = NT * 32;
    __shared__ __align__(16) ushort_t LDS[36864];   // 72 KiB -> 2 blocks/CU

    const int t = threadIdx.x;
    const int wid = t >> 6, lane = t & 63;
    const int wm = wid >> 2, wn = wid & 3;
    const int fl = lane & 15, fh = lane >> 4;

    const int orig = blockIdx.x + 32 * blockIdx.y + (32 << LNB) * blockIdx.z;
    const int q = (32 << LNB);                 // nwg/8 (gridDim.z == 8)
    const int wg = (orig & 7) * q + (orig >> 3);
    const int z = wg >> (5 + LNB);
    const int inner = wg & ((32 << LNB) - 1);
    const int bm = (inner >> LNB) * 128;
    const int bn = (inner & ((1 << LNB) - 1)) * 256;

    const ushort_t* Atile = (const ushort_t*)A + (size_t)z * sAc + (size_t)bm * lda;
    const ushort_t* Btile = (const ushort_t*)Wt + (size_t)z * sWc + (size_t)bn * K;

    const char* LDSc = (const char*)&LDS[0];
    const unsigned lanepart = fl * 64 + ((fh ^ ((fl >> 2) & 2)) << 4);
    const unsigned vA = wm * 4096 + lanepart;
    const unsigned vB = 24576 + wn * 4096 + lanepart;

    f32x4 acc[4][4];
    #pragma unroll
    for (int i = 0; i < 4; ++i)
        #pragma unroll
        for (int j = 0; j < 4; ++j) acc[i][j] = (f32x4){0.f, 0.f, 0.f, 0.f};

    stage_half256(Btile, K, &LDS[12288], t);
    stage_half128(Atile, lda, &LDS[0], t);
    stage_half256(Btile + 32, K, &LDS[12288 + 8192], t);
    stage_half128(Atile + 32, lda, &LDS[4096], t);
    asm volatile("s_waitcnt vmcnt(3)" ::: "memory");
    __builtin_amdgcn_s_barrier();
    asm volatile("" ::: "memory");

    int kt = 0;
    while (kt + 3 <= NT) { GBODY(0) GBODY(1) GBODY(2) }
    if constexpr (NT % 3 >= 1) { GBODY(0) }
    if constexpr (NT % 3 >= 2) { GBODY(1) }

    #pragma unroll
    for (int mi = 0; mi < 4; ++mi) {
        #pragma unroll
        for (int ni = 0; ni < 4; ++ni) {
            const int n = bn + wn * 64 + ni * 16 + fl;
            const float bv = bias[z * sBc + n];
            #pragma unroll
            for (int r = 0; r < 4; ++r) {
                const int m = bm + wm * 64 + mi * 16 + fh * 4 + r;
                float v = acc[mi][ni][r] + bv;
                if (MODE == 0) v = elu1(v);
                Obf[(size_t)z * sOc + (size_t)m * ldo + n] = __float2bfloat16(v);
            }
        }
    }
}

// ---------------------------------------------------------------------------
// 2-phase 128xBN kernel — kept for enc4 (N=64, MODE 1)
// ---------------------------------------------------------------------------
template<int BN, int MODE>
__global__ __launch_bounds__(256) void mfma_gemm(
    const __hip_bfloat16* __restrict__ A, size_t sAc, int lda, int K,
    const __hip_bfloat16* __restrict__ Wt, size_t sWc,
    const float* __restrict__ bias, int sBc,
    __hip_bfloat16* __restrict__ Obf, size_t sOc, int ldo,
    float* __restrict__ Of, int c0)
{
    constexpr int NI = BN / 32;
    __shared__ __align__(16) ushort_t As2[128 * 32];
    __shared__ __align__(16) ushort_t Bs2[BN * 32];

    const int t = threadIdx.x;
    const int wid = t >> 6, lane = t & 63;
    const int wm = wid >> 1, wn = wid & 1;
    const int z = blockIdx.z;
    const int bm = blockIdx.x * 128;
    const int bn = blockIdx.y * BN;

    const ushort_t* Ap = (const ushort_t*)A + (size_t)z * sAc;
    const ushort_t* Wp = (const ushort_t*)Wt + (size_t)z * sWc;

    const int srow = t >> 2;
    const int scol = (t & 3) << 3;
    const int fl = lane & 15, fh = lane >> 4;

    f32x4 zero4 = {0.f, 0.f, 0.f, 0.f};
    f32x4 acc[4][NI];
    #pragma unroll
    for (int mi = 0; mi < 4; ++mi)
        #pragma unroll
        for (int ni = 0; ni < NI; ++ni) acc[mi][ni] = zero4;

    for (int k0 = 0; k0 < K; k0 += 32) {
        #pragma unroll
        for (int i = 0; i < 2; ++i)
            gload_lds16(Ap + (size_t)(bm + i * 64 + srow) * lda + k0 + scol,
                        &As2[i * 2048 + wid * 512]);
        #pragma unroll
        for (int i = 0; i < BN / 64; ++i)
            gload_lds16(Wp + (size_t)(bn + i * 64 + srow) * K + k0 + scol,
                        &Bs2[i * 2048 + wid * 512]);
        __syncthreads();

        bf16x8 af[4], bfr[NI];
        #pragma unroll
        for (int mi = 0; mi < 4; ++mi)
            af[mi] = *(const bf16x8*)&As2[(wm * 64 + mi * 16 + fl) * 32 + fh * 8];
        #pragma unroll
        for (int ni = 0; ni < NI; ++ni)
            bfr[ni] = *(const bf16x8*)&Bs2[(wn * (BN / 2) + ni * 16 + fl) * 32 + fh * 8];
        #pragma unroll
        for (int mi = 0; mi < 4; ++mi)
            #pragma unroll
            for (int ni = 0; ni < NI; ++ni)
                acc[mi][ni] = __builtin_amdgcn_mfma_f32_16x16x32_bf16(
                    af[mi], bfr[ni], acc[mi][ni], 0, 0, 0);
        __syncthreads();
    }

    #pragma unroll
    for (int mi = 0; mi < 4; ++mi) {
        #pragma unroll
        for (int ni = 0; ni < NI; ++ni) {
            const int n = bn + wn * (BN / 2) + ni * 16 + fl;
            const float bv = bias[z * sBc + n];
            #pragma unroll
            for (int r = 0; r < 4; ++r) {
                const int m = bm + wm * 64 + mi * 16 + fh * 4 + r;
                float v = acc[mi][ni][r] + bv;
                if (MODE == 0) v = elu1(v);
                Obf[(size_t)z * sOc + (size_t)m * ldo + n] = __float2bfloat16(v);
                if (MODE == 1)
                    Of[(size_t)m * 512 + (size_t)(c0 + z) * 64 + n] = v;
            }
        }
    }
}

// fp32 [K][N] -> bf16 [N][K] (transpose + convert) — single-layer (fallback)
__global__ __launch_bounds__(256) void cvtT(
    const float* __restrict__ in, __hip_bfloat16* __restrict__ out,
    int K, int N, size_t sInC, size_t sOutC)
{
    __shared__ float tile[32][33];
    const float* ip = in + blockIdx.z * sInC;
    __hip_bfloat16* op = out + blockIdx.z * sOutC;
    const int n0 = blockIdx.x * 32, k0 = blockIdx.y * 32;
    const int x = threadIdx.x, y = threadIdx.y;
    #pragma unroll
    for (int j = 0; j < 4; ++j)
        tile[y + 8 * j][x] = ip[(size_t)(k0 + y + 8 * j) * N + n0 + x];
    __syncthreads();
    #pragma unroll
    for (int j = 0; j < 4; ++j)
        op[(size_t)(n0 + y + 8 * j) * K + k0 + x] = __float2bfloat16(tile[x][y + 8 * j]);
}

// ALL 8 weight layers in ONE launch. Job table passed by value.
struct CvtJobs {
    const float* in[8];
    __hip_bfloat16* out[8];
    int N[8], K[8], ntn[8], npc[8], end[8];
};

__global__ __launch_bounds__(256) void cvt_pass(CvtJobs j)
{
    __shared__ float tile[32][33];
    int bid = blockIdx.x;
    int l = 0;
    while (bid >= j.end[l]) ++l;            // uniform scan, <=8
    const int start = l ? j.end[l - 1] : 0;
    const int local = bid - start;
    const int chart = local / j.npc[l];
    const int rem = local - chart * j.npc[l];
    const int K = j.K[l], N = j.N[l];
    const int n0 = (rem % j.ntn[l]) * 32;
    const int k0 = (rem / j.ntn[l]) * 32;
    const float* ip = j.in[l] + (size_t)chart * K * N;
    __hip_bfloat16* op = j.out[l] + (size_t)chart * K * N;
    const int x = threadIdx.x, y = threadIdx.y;
    #pragma unroll
    for (int jj = 0; jj < 4; ++jj)
        tile[y + 8 * jj][x] = ip[(size_t)(k0 + y + 8 * jj) * N + n0 + x];
    __syncthreads();
    #pragma unroll
    for (int jj = 0; jj < 4; ++jj)
        op[(size_t)(n0 + y + 8 * jj) * K + k0 + x] =
            __float2bfloat16(tile[x][y + 8 * jj]);
}

// recon_x + recon_errors + ALL losses + finalize in one launch (G=8 path).
// One wave per row; er[8], p, recon row all in registers. Last-block ticket.
__global__ __launch_bounds__(256) void recon_losses(
    const float* __restrict__ x, const __hip_bfloat16* __restrict__ xrec,
    const float* __restrict__ p, float* __restrict__ recon_x,
    float* __restrict__ acc, float* __restrict__ scal, int nblocks)
{
    __shared__ float s[11];
    const int t = threadIdx.x;
    if (t < 11) s[t] = 0.f;
    __syncthreads();

    const int wid = t >> 6, lane = t & 63;
    const size_t b = (size_t)blockIdx.x * 4 + wid;
    const float4* xp = (const float4*)(x + b * 512);
    const float4 x0 = xp[lane * 2], x1 = xp[lane * 2 + 1];
    const float xv[8] = {x0.x, x0.y, x0.z, x0.w, x1.x, x1.y, x1.z, x1.w};
    float r[8] = {0.f, 0.f, 0.f, 0.f, 0.f, 0.f, 0.f, 0.f};
    float er[8], pr[8];

    #pragma unroll
    for (int cc = 0; cc < 8; ++cc) {
        const ushort_t* xr =
            (const ushort_t*)xrec + ((size_t)cc * 4096 + b) * 512 + lane * 8;
        bf16x8 v = *(const bf16x8*)xr;
        float pv = p[b * 8 + cc];
        pr[cc] = pv;
        float e = 0.f;
        #pragma unroll
        for (int jj = 0; jj < 8; ++jj) {
            float f = (float)v[jj];
            r[jj] = fmaf(pv, f, r[jj]);
            float d = xv[jj] - f;
            e = fmaf(d, d, e);
        }
        #pragma unroll
        for (int off = 1; off < 64; off <<= 1) e += __shfl_xor(e, off, 64);
        er[cc] = e;
    }

    // recon_x (single pass, no accumulate)
    float4* op = (float4*)(recon_x + b * 512);
    op[lane * 2]     = (float4){r[0], r[1], r[2], r[3]};
    op[lane * 2 + 1] = (float4){r[4], r[5], r[6], r[7]};

    // mse partial from registers
    float sm = 0.f;
    #pragma unroll
    for (int jj = 0; jj < 8; ++jj) {
        float d = r[jj] - xv[jj];
        sm = fmaf(d, d, sm);
    }
    #pragma unroll
    for (int off = 1; off < 64; off <<= 1) sm += __shfl_xor(sm, off, 64);
    if (lane == 0) atomicAdd(&s[10], sm);

    // per-row losses at lane 0 (er/pr resident)
    if (lane == 0) {
        float mn = er[0];
        #pragma unroll
        for (int c = 1; c < 8; ++c) mn = fminf(mn, er[c]);
        float qv[8], se = 0.f;
        #pragma unroll
        for (int c = 0; c < 8; ++c) { qv[c] = expf(mn - er[c]); se += qv[c]; }
        float rl = 0.f, tl = 0.f;
        #pragma unroll
        for (int c = 0; c < 8; ++c) {
            rl = fmaf(pr[c], er[c], rl);
            tl = fmaf(qv[c] / se, logf(pr[c] + 1e-8f), tl);
        }
        atomicAdd(&s[0], rl);
        atomicAdd(&s[1], tl);
        #pragma unroll
        for (int c = 0; c < 8; ++c) atomicAdd(&s[2 + c], pr[c]);
    }
    __syncthreads();

    if (t < 11) {
        atomicAdd(&acc[t], s[t]);
        __threadfence();
    }
    __syncthreads();

    if (t == 0) {
        unsigned tk = atomicAdd((unsigned*)&acc[12], 1u);
        if (tk == (unsigned)(nblocks - 1)) {
            volatile float* va = acc;
            const float invB = 1.f / 4096.f;
            float recon = va[0] * invB;
            float trans = -va[1] * invB;
            float nondom = 0.f;
            for (int c = 0; c < 8; ++c) {
                float mp = va[2 + c] * invB;
                float d = mp - 0.125f;
                nondom = fmaf(d, d, nondom);
            }
            float mse = va[10] / (4096.f * 512.f);
            scal[0] = recon + trans + nondom;
            scal[1] = recon;
            scal[2] = nondom;
            scal[3] = trans;
            scal[4] = mse;
        }
    }
}

// fallback kernels (old path) ------------------------------------------------
__global__ __launch_bounds__(256) void recon_group(
    const float* __restrict__ x, const __hip_bfloat16* __restrict__ xrec,
    const float* __restrict__ p, float* __restrict__ recon_x,
    float* __restrict__ err, int c0, int G)
{
    const int wid = threadIdx.x >> 6, lane = threadIdx.x & 63;
    const size_t b = (size_t)blockIdx.x * 4 + wid;
    const float4* xp = (const float4*)(x + b * 512);
    const float4 x0 = xp[lane * 2], x1 = xp[lane * 2 + 1];
    const float xv[8] = {x0.x, x0.y, x0.z, x0.w, x1.x, x1.y, x1.z, x1.w};
    float r[8] = {0.f, 0.f, 0.f, 0.f, 0.f, 0.f, 0.f, 0.f};

    for (int cc = 0; cc < G; ++cc) {
        const ushort_t* xr =
            (const ushort_t*)xrec + ((size_t)cc * 4096 + b) * 512 + lane * 8;
        bf16x8 v = *(const bf16x8*)xr;
        float pv = p[b * 8 + c0 + cc];
        float e = 0.f;
        #pragma unroll
        for (int jj = 0; jj < 8; ++jj) {
            float f = (float)v[jj];
            r[jj] = fmaf(pv, f, r[jj]);
            float d = xv[jj] - f;
            e = fmaf(d, d, e);
        }
        #pragma unroll
        for (int off = 1; off < 64; off <<= 1) e += __shfl_xor(e, off, 64);
        if (lane == 0) err[b * 8 + c0 + cc] = e;
    }

    float4* op = (float4*)(recon_x + b * 512);
    float4 o0 = {r[0], r[1], r[2], r[3]}, o1 = {r[4], r[5], r[6], r[7]};
    if (c0) {
        float4 t0 = op[lane * 2], t1 = op[lane * 2 + 1];
        o0.x += t0.x; o0.y += t0.y; o0.z += t0.z; o0.w += t0.w;
        o1.x += t1.x; o1.y += t1.y; o1.z += t1.z; o1.w += t1.w;
    }
    op[lane * 2] = o0;
    op[lane * 2 + 1] = o1;
}

__global__ __launch_bounds__(256) void tail_reduce(
    const float* __restrict__ p, const float* __restrict__ err,
    const float* __restrict__ recon_x, const float* __restrict__ x,
    float* __restrict__ acc, float* __restrict__ scal,
    int B, int D, int nblocks)
{
    __shared__ float s[11];
    const int t = threadIdx.x;
    if (t < 11) s[t] = 0.f;
    __syncthreads();
    int b = blockIdx.x * 256 + t;
    if (b < B) {
        float pr[8], er[8];
        #pragma unroll
        for (int c = 0; c < 8; ++c) { pr[c] = p[b * 8 + c]; er[c] = err[b * 8 + c]; }
        float mn = er[0];
        #pragma unroll
        for (int c = 1; c < 8; ++c) mn = fminf(mn, er[c]);
        float q[8], se = 0.f;
        #pragma unroll
        for (int c = 0; c < 8; ++c) { q[c] = expf(mn - er[c]); se += q[c]; }
        float rl = 0.f, tl = 0.f;
        #pragma unroll
        for (int c = 0; c < 8; ++c) {
            rl = fmaf(pr[c], er[c], rl);
            tl = fmaf(q[c] / se, logf(pr[c] + 1e-8f), tl);
        }
        atomicAdd(&s[0], rl);
        atomicAdd(&s[1], tl);
        #pragma unroll
        for (int c = 0; c < 8; ++c) atomicAdd(&s[2 + c], pr[c]);
    }
    float sm = 0.f;
    const int n = B * D;
    for (int i = blockIdx.x * 256 + t; i < n; i += nblocks * 256) {
        float d = recon_x[i] - x[i];
        sm = fmaf(d, d, sm);
    }
    atomicAdd(&s[10], sm);
    __syncthreads();
    if (t < 11) { atomicAdd(&acc[t], s[t]); __threadfence(); }
    __syncthreads();
    if (t == 0) {
        unsigned tk = atomicAdd((unsigned*)&acc[12], 1u);
        if (tk == (unsigned)(nblocks - 1)) {
            volatile float* va = acc;
            float invB = 1.f / (float)B;
            float recon = va[0] * invB;
            float trans = -va[1] * invB;
            float nondom = 0.f;
            for (int c = 0; c < 8; ++c) {
                float mp = va[2 + c] * invB;
                float d = mp - 0.125f;
                nondom = fmaf(d, d, nondom);
            }
            float mse = va[10] / ((float)B * (float)D);
            scal[0] = recon + trans + nondom;
            scal[1] = recon;
            scal[2] = nondom;
            scal[3] = trans;
            scal[4] = mse;
        }
    }
}
// ----------------------------------------------------------------------------

__global__ __launch_bounds__(256) void proj_sparsemax(
    const float* __restrict__ x, const float* __restrict__ Wp,
    const float* __restrict__ bp, float* __restrict__ p,
    __hip_bfloat16* __restrict__ xbf, int B, int D)
{
    int gw = (blockIdx.x * blockDim.x + threadIdx.x) >> 6;
    int lane = threadIdx.x & 63;
    if (gw >= B) return;
    const float* xr = x + (size_t)gw * D;
    __hip_bfloat16* xo = xbf + (size_t)gw * D;
    float acc[8] = {0.f, 0.f, 0.f, 0.f, 0.f, 0.f, 0.f, 0.f};
    for (int d = lane; d < D; d += 64) {
        float xv = xr[d];
        xo[d] = __float2bfloat16(xv);
        #pragma unroll
        for (int c = 0; c < 8; ++c) acc[c] = fmaf(xv, Wp[d * 8 + c], acc[c]);
    }
    #pragma unroll
    for (int off = 32; off > 0; off >>= 1) {
        #pragma unroll
        for (int c = 0; c < 8; ++c) acc[c] += __shfl_xor(acc[c], off, 64);
    }
    if (lane == 0) {
        float s[8], zs[8];
        #pragma unroll
        for (int c = 0; c < 8; ++c) { s[c] = acc[c] + bp[c]; zs[c] = s[c]; }
        for (int i = 1; i < 8; ++i) {
            float v = zs[i];
            int j = i - 1;
            while (j >= 0 && zs[j] < v) { zs[j + 1] = zs[j]; --j; }
            zs[j + 1] = v;
        }
        float cs = 0.f, csel = 1.f;
        int kz = 1;
        for (int k = 1; k <= 8; ++k) {
            cs += zs[k - 1];
            if (1.f + (float)k * zs[k - 1] > cs) { kz = k; csel = cs; }
        }
        float tau = (csel - 1.f) / (float)kz;
        #pragma unroll
        for (int c = 0; c < 8; ++c) p[gw * 8 + c] = fmaxf(s[c] - tau, 0.f);
    }
}

extern "C" void kernel_launch(void* const* d_in, const int* in_sizes, int n_in,
                              void* d_out, int out_size, void* d_ws, size_t ws_size,
                              hipStream_t stream)
{
    const int B = 4096, D = 512, L = 64, H = 1024, C = 8;

    const float* x   = (const float*)d_in[0];
    const float* We1 = (const float*)d_in[1];
    const float* be1 = (const float*)d_in[2];
    const float* We2 = (const float*)d_in[3];
    const float* be2 = (const float*)d_in[4];
    const float* We3 = (const float*)d_in[5];
    const float* be3 = (const float*)d_in[6];
    const float* We4 = (const float*)d_in[7];
    const float* be4 = (const float*)d_in[8];
    const float* Wd1 = (const float*)d_in[9];
    const float* bd1 = (const float*)d_in[10];
    const float* Wd2 = (const float*)d_in[11];
    const float* bd2 = (const float*)d_in[12];
    const float* Wd3 = (const float*)d_in[13];
    const float* bd3 = (const float*)d_in[14];
    const float* Wd4 = (const float*)d_in[15];
    const float* bd4 = (const float*)d_in[16];
    const float* Wp  = (const float*)d_in[17];
    const float* bp  = (const float*)d_in[18];

    float* out     = (float*)d_out;
    float* recon_x = out;                          // [B,D]
    float* zfp     = out + (size_t)B * D;          // [B,C,L]
    float* p       = zfp + (size_t)B * C * L;      // [B,C]
    float* scal    = p + (size_t)B * C;            // 5 scalars

    const dim3 cb(32, 8);
    const dim3 gSH(32, 4, 8);   // 128x256 tiles, N=1024
    const dim3 gSD(32, 2, 8);   // N=512

    // --- big-workspace path: all weights converted once, fused tail ---
    const size_t eHD = (size_t)C * H * D;   // enc1 / dec4 elems
    const size_t eHH = (size_t)C * H * H;
    const size_t eHL = (size_t)C * H * L;
    const size_t bigNeed = ((size_t)B * D + (size_t)C * B * L +
                            2 * eHD + 4 * eHH + 2 * eHL +
                            2ull * C * B * H + (size_t)C * B * D) * 2ull + 4096;

    if (ws_size >= bigNeed) {
        char* w = (char*)d_ws;
        __hip_bfloat16* xbf  = (__hip_bfloat16*)w; w += (size_t)B * D * 2;
        __hip_bfloat16* zbf  = (__hip_bfloat16*)w; w += (size_t)C * B * L * 2;
        __hip_bfloat16* wE1  = (__hip_bfloat16*)w; w += eHD * 2;
        __hip_bfloat16* wE2  = (__hip_bfloat16*)w; w += eHH * 2;
        __hip_bfloat16* wE3  = (__hip_bfloat16*)w; w += eHH * 2;
        __hip_bfloat16* wE4  = (__hip_bfloat16*)w; w += eHL * 2;
        __hip_bfloat16* wD1  = (__hip_bfloat16*)w; w += eHL * 2;
        __hip_bfloat16* wD2  = (__hip_bfloat16*)w; w += eHH * 2;
        __hip_bfloat16* wD3  = (__hip_bfloat16*)w; w += eHH * 2;
        __hip_bfloat16* wD4  = (__hip_bfloat16*)w; w += eHD * 2;
        __hip_bfloat16* hA   = (__hip_bfloat16*)w; w += (size_t)C * B * H * 2;
        __hip_bfloat16* hB   = (__hip_bfloat16*)w; w += (size_t)C * B * H * 2;
        __hip_bfloat16* xrec = (__hip_bfloat16*)w; w += (size_t)C * B * D * 2;
        float* acc = (float*)w;

        hipMemsetAsync(acc, 0, 16 * sizeof(float), stream);
        proj_sparsemax<<<B / 4, 256, 0, stream>>>(x, Wp, bp, p, xbf, B, D);

        // one launch: convert+transpose all 8 weight layers
        CvtJobs j;
        const float* ins[8]  = {We1, We2, We3, We4, Wd1, Wd2, Wd3, Wd4};
        __hip_bfloat16* outs[8] = {wE1, wE2, wE3, wE4, wD1, wD2, wD3, wD4};
        int Ks[8] = {D, H, H, H, L, H, H, H};
        int Ns[8] = {H, H, H, L, H, H, H, D};
        int total = 0;
        for (int l = 0; l < 8; ++l) {
            j.in[l] = ins[l]; j.out[l] = outs[l];
            j.K[l] = Ks[l]; j.N[l] = Ns[l];
            j.ntn[l] = Ns[l] / 32;
            j.npc[l] = (Ns[l] / 32) * (Ks[l] / 32);
            total += j.npc[l] * 8;
            j.end[l] = total;
        }
        cvt_pass<<<total, cb, 0, stream>>>(j);

        gemmS<0, 16, 2><<<gSH, 512, 0, stream>>>(
            xbf, 0, D, wE1, (size_t)H * D, be1, H, hA, (size_t)B * H, H);
        gemmS<0, 32, 2><<<gSH, 512, 0, stream>>>(
            hA, (size_t)B * H, H, wE2, (size_t)H * H, be2, H, hB, (size_t)B * H, H);
        gemmS<0, 32, 2><<<gSH, 512, 0, stream>>>(
            hB, (size_t)B * H, H, wE3, (size_t)H * H, be3, H, hA, (size_t)B * H, H);
        mfma_gemm<64, 1><<<dim3(32, 1, 8), 256, 0, stream>>>(
            hA, (size_t)B * H, H, H, wE4, (size_t)L * H, be4, L,
            zbf, (size_t)B * L, L, zfp, 0);
        gemmS<0, 2, 2><<<gSH, 512, 0, stream>>>(
            zbf, (size_t)B * L, L, wD1, (size_t)H * L, bd1, H, hB, (size_t)B * H, H);
        gemmS<0, 32, 2><<<gSH, 512, 0, stream>>>(
            hB, (size_t)B * H, H, wD2, (size_t)H * H, bd2, H, hA, (size_t)B * H, H);
        gemmS<0, 32, 2><<<gSH, 512, 0, stream>>>(
            hA, (size_t)B * H, H, wD3, (size_t)H * H, bd3, H, hB, (size_t)B * H, H);
        gemmS<2, 32, 1><<<gSD, 512, 0, stream>>>(
            hB, (size_t)B * H, H, wD4, (size_t)D * H, bd4, D, xrec, (size_t)B * D, D);

        recon_losses<<<B / 4, 256, 0, stream>>>(x, xrec, p, recon_x, acc, scal, B / 4);
        return;
    }

    // --- fallback: R13 path (per-layer cvtT, grouped charts) ---
    const size_t perG = ((size_t)H * H + 2ull * B * H + (size_t)B * D) * 2ull;
    const size_t fixedB = ((size_t)B * D + (size_t)C * B * L) * 2ull +
                          ((size_t)B * C + 16) * 4ull + 1024;
    int G = 8;
    while (G > 1 && fixedB + perG * (size_t)G > ws_size) G >>= 1;

    char* w = (char*)d_ws;
    __hip_bfloat16* xbf  = (__hip_bfloat16*)w; w += (size_t)B * D * 2;
    __hip_bfloat16* zbf  = (__hip_bfloat16*)w; w += (size_t)C * B * L * 2;
    __hip_bfloat16* wbuf = (__hip_bfloat16*)w; w += (size_t)G * H * H * 2;
    __hip_bfloat16* hA   = (__hip_bfloat16*)w; w += (size_t)G * B * H * 2;
    __hip_bfloat16* hB   = (__hip_bfloat16*)w; w += (size_t)G * B * H * 2;
    __hip_bfloat16* xrec = (__hip_bfloat16*)w; w += (size_t)G * B * D * 2;
    float* err = (float*)w; w += (size_t)B * C * 4;
    float* acc = (float*)w;

    hipMemsetAsync(acc, 0, 16 * sizeof(float), stream);
    proj_sparsemax<<<B / 4, 256, 0, stream>>>(x, Wp, bp, p, xbf, B, D);

    for (int c0 = 0; c0 < C; c0 += G) {
        cvtT<<<dim3(H / 32, D / 32, G), cb, 0, stream>>>(
            We1 + (size_t)c0 * D * H, wbuf, D, H, (size_t)D * H, (size_t)D * H);
        gemmS<0, 16, 2><<<gSH, 512, 0, stream>>>(
            xbf, 0, D, wbuf, (size_t)D * H, be1 + (size_t)c0 * H, H,
            hA, (size_t)B * H, H);
        cvtT<<<dim3(H / 32, H / 32, G), cb, 0, stream>>>(
            We2 + (size_t)c0 * H * H, wbuf, H, H, (size_t)H * H, (size_t)H * H);
        gemmS<0, 32, 2><<<gSH, 512, 0, stream>>>(
            hA, (size_t)B * H, H, wbuf, (size_t)H * H, be2 + (size_t)c0 * H, H,
            hB, (size_t)B * H, H);
        cvtT<<<dim3(H / 32, H / 32, G), cb, 0, stream>>>(
            We3 + (size_t)c0 * H * H, wbuf, H, H, (size_t)H * H, (size_t)H * H);
        gemmS<0, 32, 2><<<gSH, 512, 0, stream>>>(
            hB, (size_t)B * H, H, wbuf, (size_t)H * H, be3 + (size_t)c0 * H, H,
            hA, (size_t)B * H, H);
        cvtT<<<dim3(L / 32, H / 32, G), cb, 0, stream>>>(
            We4 + (size_t)c0 * H * L, wbuf, H, L, (size_t)H * L, (size_t)H * L);
        mfma_gemm<64, 1><<<dim3(32, 1, G), 256, 0, stream>>>(
            hA, (size_t)B * H, H, H, wbuf, (size_t)H * L, be4 + (size_t)c0 * L, L,
            zbf + (size_t)c0 * B * L, (size_t)B * L, L, zfp, c0);
        cvtT<<<dim3(H / 32, L / 32, G), cb, 0, stream>>>(
            Wd1 + (size_t)c0 * L * H, wbuf, L, H, (size_t)L * H, (size_t)L * H);
        gemmS<0, 2, 2><<<gSH, 512, 0, stream>>>(
            zbf + (size_t)c0 * B * L, (size_t)B * L, L, wbuf, (size_t)L * H,
            bd1 + (size_t)c0 * H, H, hB, (size_t)B * H, H);
        cvtT<<<dim3(H / 32, H / 32, G), cb, 0, stream>>>(
            Wd2 + (size_t)c0 * H * H, wbuf, H, H, (size_t)H * H, (size_t)H * H);
        gemmS<0, 32, 2><<<gSH, 512, 0, stream>>>(
            hB, (size_t)B * H, H, wbuf, (size_t)H * H, bd2 + (size_t)c0 * H, H,
            hA, (size_t)B * H, H);
        cvtT<<<dim3(H / 32, H / 32, G), cb, 0, stream>>>(
            Wd3 + (size_t)c0 * H * H, wbuf, H, H, (size_t)H * H, (size_t)H * H);
        gemmS<0, 32, 2><<<gSH, 512, 0, stream>>>(
            hA, (size_t)B * H, H, wbuf, (size_t)H * H, bd3 + (size_t)c0 * H, H,
            hB, (size_t)B * H, H);
        cvtT<<<dim3(D / 32, H / 32, G), cb, 0, stream>>>(
            Wd4 + (size_t)c0 * H * D, wbuf, H, D, (size_t)H * D, (size_t)H * D);
        gemmS<2, 32, 1><<<gSD, 512, 0, stream>>>(
            hB, (size_t)B * H, H, wbuf, (size_t)H * D, bd4 + (size_t)c0 * D, D,
            xrec, (size_t)B * D, D);
        recon_group<<<B / 4, 256, 0, stream>>>(x, xrec, p, recon_x, err, c0, G);
    }

    tail_reduce<<<1024, 256, 0, stream>>>(p, err, recon_x, x, acc, scal, B, D, 1024);
}

// Round 15
// 571.133 us; speedup vs baseline: 8.9604x; 1.0145x over previous
//
#include <hip/hip_runtime.h>
#include <hip/hip_bf16.h>

typedef unsigned short ushort_t;
typedef __bf16 bf16x8 __attribute__((ext_vector_type(8)));
typedef float f32x4 __attribute__((ext_vector_type(4)));

__device__ __forceinline__ void gload_lds16(const void* g, void* l) {
    __builtin_amdgcn_global_load_lds(
        (const __attribute__((address_space(1))) void*)g,
        (__attribute__((address_space(3))) void*)l, 16, 0, 0);
}

__device__ __forceinline__ float elu1(float v) { return v > 0.f ? v : expm1f(v); }

// stage [256 rows][32 k] bf16 (16 KiB): 2 loads/thread (512 thr). LDS dest
// linear (t*16B), global source pre-swizzled: chunk bit1 ^= row bit3 (st_16x32).
__device__ __forceinline__ void stage_half256(const ushort_t* g, int ldg,
                                              ushort_t* lds, int t) {
    const int row = t >> 2;
    const int chunk = (t & 3) ^ ((t >> 4) & 2);
    const ushort_t* src = g + (size_t)row * ldg + chunk * 8;
    const int wo = (t >> 6) * 512;
    gload_lds16(src, lds + wo);
    gload_lds16(src + (size_t)128 * ldg, lds + 4096 + wo);
}
// stage [128 rows][32 k] (8 KiB): 1 load/thread
__device__ __forceinline__ void stage_half128(const ushort_t* g, int ldg,
                                              ushort_t* lds, int t) {
    const int row = t >> 2;
    const int chunk = (t & 3) ^ ((t >> 4) & 2);
    gload_lds16(g + (size_t)row * ldg + chunk * 8, lds + (t >> 6) * 512);
}

// ---------------------------------------------------------------------------
// 128x256 MFMA GEMM, BK=32, 8 waves (2M x 4N), 64x64/wave (acc[4][4]).
// R11 champion (FROZEN): ONE barrier/kt, compiler lgkm waits, counted
// vmcnt(3), 3-deep rotation w/ STATIC buffer offsets, bn-low L2 ordering.
// LDS (ushorts): A @ 0,4096,8192 ; B @ 12288,20480,28672.
// ---------------------------------------------------------------------------
#define LDA(J_, MI_) (*(const bf16x8*)(LDSc + vA + ((J_) * 8192 + (MI_) * 1024)))
#define LDB(J_, NI_) (*(const bf16x8*)(LDSc + vB + ((J_) * 16384 + (NI_) * 1024)))

#define GBODY(J_)                                                              \
  {                                                                            \
    bf16x8 a0 = LDA(J_, 0), a1 = LDA(J_, 1), a2 = LDA(J_, 2), a3 = LDA(J_, 3); \
    bf16x8 b0 = LDB(J_, 0), b1 = LDB(J_, 1), b2 = LDB(J_, 2), b3 = LDB(J_, 3); \
    if (kt + 2 < NT) {                                                         \
      constexpr int W_ = ((J_) + 2) % 3;                                       \
      stage_half256(Btile + (size_t)(kt + 2) * 32, K, &LDS[12288 + W_ * 8192], t); \
      stage_half128(Atile + (size_t)(kt + 2) * 32, lda, &LDS[W_ * 4096], t);   \
    }                                                                          \
    __builtin_amdgcn_s_setprio(1);                                             \
    acc[0][0] = __builtin_amdgcn_mfma_f32_16x16x32_bf16(a0, b0, acc[0][0], 0, 0, 0); \
    acc[0][1] = __builtin_amdgcn_mfma_f32_16x16x32_bf16(a0, b1, acc[0][1], 0, 0, 0); \
    acc[0][2] = __builtin_amdgcn_mfma_f32_16x16x32_bf16(a0, b2, acc[0][2], 0, 0, 0); \
    acc[0][3] = __builtin_amdgcn_mfma_f32_16x16x32_bf16(a0, b3, acc[0][3], 0, 0, 0); \
    acc[1][0] = __builtin_amdgcn_mfma_f32_16x16x32_bf16(a1, b0, acc[1][0], 0, 0, 0); \
    acc[1][1] = __builtin_amdgcn_mfma_f32_16x16x32_bf16(a1, b1, acc[1][1], 0, 0, 0); \
    acc[1][2] = __builtin_amdgcn_mfma_f32_16x16x32_bf16(a1, b2, acc[1][2], 0, 0, 0); \
    acc[1][3] = __builtin_amdgcn_mfma_f32_16x16x32_bf16(a1, b3, acc[1][3], 0, 0, 0); \
    acc[2][0] = __builtin_amdgcn_mfma_f32_16x16x32_bf16(a2, b0, acc[2][0], 0, 0, 0); \
    acc[2][1] = __builtin_amdgcn_mfma_f32_16x16x32_bf16(a2, b1, acc[2][1], 0, 0, 0); \
    acc[2][2] = __builtin_amdgcn_mfma_f32_16x16x32_bf16(a2, b2, acc[2][2], 0, 0, 0); \
    acc[2][3] = __builtin_amdgcn_mfma_f32_16x16x32_bf16(a2, b3, acc[2][3], 0, 0, 0); \
    acc[3][0] = __builtin_amdgcn_mfma_f32_16x16x32_bf16(a3, b0, acc[3][0], 0, 0, 0); \
    acc[3][1] = __builtin_amdgcn_mfma_f32_16x16x32_bf16(a3, b1, acc[3][1], 0, 0, 0); \
    acc[3][2] = __builtin_amdgcn_mfma_f32_16x16x32_bf16(a3, b2, acc[3][2], 0, 0, 0); \
    acc[3][3] = __builtin_amdgcn_mfma_f32_16x16x32_bf16(a3, b3, acc[3][3], 0, 0, 0); \
    __builtin_amdgcn_s_setprio(0);                                             \
    if (kt < NT - 2) asm volatile("s_waitcnt vmcnt(3)" ::: "memory");          \
    else             asm volatile("s_waitcnt vmcnt(0)" ::: "memory");          \
    __builtin_amdgcn_s_barrier();                                              \
    asm volatile("" ::: "memory");                                             \
    ++kt;                                                                      \
  }

template<int MODE, int NT, int LNB>
__global__ __launch_bounds__(512, 4) void gemmS(
    const __hip_bfloat16* __restrict__ A, size_t sAc, int lda,
    const __hip_bfloat16* __restrict__ Wt, size_t sWc,
    const float* __restrict__ bias, int sBc,
    __hip_bfloat16* __restrict__ Obf, size_t sOc, int ldo)
{
    constexpr int K = NT * 32;
    __shared__ __align__(16) ushort_t LDS[36864];   // 72 KiB -> 2 blocks/CU

    const int t = threadIdx.x;
    const int wid = t >> 6, lane = t & 63;
    const int wm = wid >> 2, wn = wid & 3;
    const int fl = lane & 15, fh = lane >> 4;

    const int orig = blockIdx.x + 32 * blockIdx.y + (32 << LNB) * blockIdx.z;
    const int q = (32 << LNB);                 // nwg/8 (gridDim.z == 8)
    const int wg = (orig & 7) * q + (orig >> 3);
    const int z = wg >> (5 + LNB);
    const int inner = wg & ((32 << LNB) - 1);
    const int bm = (inner >> LNB) * 128;
    const int bn = (inner & ((1 << LNB) - 1)) * 256;

    const ushort_t* Atile = (const ushort_t*)A + (size_t)z * sAc + (size_t)bm * lda;
    const ushort_t* Btile = (const ushort_t*)Wt + (size_t)z * sWc + (size_t)bn * K;

    const char* LDSc = (const char*)&LDS[0];
    const unsigned lanepart = fl * 64 + ((fh ^ ((fl >> 2) & 2)) << 4);
    const unsigned vA = wm * 4096 + lanepart;
    const unsigned vB = 24576 + wn * 4096 + lanepart;

    f32x4 acc[4][4];
    #pragma unroll
    for (int i = 0; i < 4; ++i)
        #pragma unroll
        for (int j = 0; j < 4; ++j) acc[i][j] = (f32x4){0.f, 0.f, 0.f, 0.f};

    stage_half256(Btile, K, &LDS[12288], t);
    stage_half128(Atile, lda, &LDS[0], t);
    stage_half256(Btile + 32, K, &LDS[12288 + 8192], t);
    stage_half128(Atile + 32, lda, &LDS[4096], t);
    asm volatile("s_waitcnt vmcnt(3)" ::: "memory");
    __builtin_amdgcn_s_barrier();
    asm volatile("" ::: "memory");

    int kt = 0;
    while (kt + 3 <= NT) { GBODY(0) GBODY(1) GBODY(2) }
    if constexpr (NT % 3 >= 1) { GBODY(0) }
    if constexpr (NT % 3 >= 2) { GBODY(1) }

    #pragma unroll
    for (int mi = 0; mi < 4; ++mi) {
        #pragma unroll
        for (int ni = 0; ni < 4; ++ni) {
            const int n = bn + wn * 64 + ni * 16 + fl;
            const float bv = bias[z * sBc + n];
            #pragma unroll
            for (int r = 0; r < 4; ++r) {
                const int m = bm + wm * 64 + mi * 16 + fh * 4 + r;
                float v = acc[mi][ni][r] + bv;
                if (MODE == 0) v = elu1(v);
                Obf[(size_t)z * sOc + (size_t)m * ldo + n] = __float2bfloat16(v);
            }
        }
    }
}

// ---------------------------------------------------------------------------
// 2-phase 128xBN kernel — kept for enc4 (N=64, MODE 1)
// ---------------------------------------------------------------------------
template<int BN, int MODE>
__global__ __launch_bounds__(256) void mfma_gemm(
    const __hip_bfloat16* __restrict__ A, size_t sAc, int lda, int K,
    const __hip_bfloat16* __restrict__ Wt, size_t sWc,
    const float* __restrict__ bias, int sBc,
    __hip_bfloat16* __restrict__ Obf, size_t sOc, int ldo,
    float* __restrict__ Of, int c0)
{
    constexpr int NI = BN / 32;
    __shared__ __align__(16) ushort_t As2[128 * 32];
    __shared__ __align__(16) ushort_t Bs2[BN * 32];

    const int t = threadIdx.x;
    const int wid = t >> 6, lane = t & 63;
    const int wm = wid >> 1, wn = wid & 1;
    const int z = blockIdx.z;
    const int bm = blockIdx.x * 128;
    const int bn = blockIdx.y * BN;

    const ushort_t* Ap = (const ushort_t*)A + (size_t)z * sAc;
    const ushort_t* Wp = (const ushort_t*)Wt + (size_t)z * sWc;

    const int srow = t >> 2;
    const int scol = (t & 3) << 3;
    const int fl = lane & 15, fh = lane >> 4;

    f32x4 zero4 = {0.f, 0.f, 0.f, 0.f};
    f32x4 acc[4][NI];
    #pragma unroll
    for (int mi = 0; mi < 4; ++mi)
        #pragma unroll
        for (int ni = 0; ni < NI; ++ni) acc[mi][ni] = zero4;

    for (int k0 = 0; k0 < K; k0 += 32) {
        #pragma unroll
        for (int i = 0; i < 2; ++i)
            gload_lds16(Ap + (size_t)(bm + i * 64 + srow) * lda + k0 + scol,
                        &As2[i * 2048 + wid * 512]);
        #pragma unroll
        for (int i = 0; i < BN / 64; ++i)
            gload_lds16(Wp + (size_t)(bn + i * 64 + srow) * K + k0 + scol,
                        &Bs2[i * 2048 + wid * 512]);
        __syncthreads();

        bf16x8 af[4], bfr[NI];
        #pragma unroll
        for (int mi = 0; mi < 4; ++mi)
            af[mi] = *(const bf16x8*)&As2[(wm * 64 + mi * 16 + fl) * 32 + fh * 8];
        #pragma unroll
        for (int ni = 0; ni < NI; ++ni)
            bfr[ni] = *(const bf16x8*)&Bs2[(wn * (BN / 2) + ni * 16 + fl) * 32 + fh * 8];
        #pragma unroll
        for (int mi = 0; mi < 4; ++mi)
            #pragma unroll
            for (int ni = 0; ni < NI; ++ni)
                acc[mi][ni] = __builtin_amdgcn_mfma_f32_16x16x32_bf16(
                    af[mi], bfr[ni], acc[mi][ni], 0, 0, 0);
        __syncthreads();
    }

    #pragma unroll
    for (int mi = 0; mi < 4; ++mi) {
        #pragma unroll
        for (int ni = 0; ni < NI; ++ni) {
            const int n = bn + wn * (BN / 2) + ni * 16 + fl;
            const float bv = bias[z * sBc + n];
            #pragma unroll
            for (int r = 0; r < 4; ++r) {
                const int m = bm + wm * 64 + mi * 16 + fh * 4 + r;
                float v = acc[mi][ni][r] + bv;
                if (MODE == 0) v = elu1(v);
                Obf[(size_t)z * sOc + (size_t)m * ldo + n] = __float2bfloat16(v);
                if (MODE == 1)
                    Of[(size_t)m * 512 + (size_t)(c0 + z) * 64 + n] = v;
            }
        }
    }
}

// fp32 [K][N] -> bf16 [N][K] (transpose + convert) — single-layer (fallback)
__global__ __launch_bounds__(256) void cvtT(
    const float* __restrict__ in, __hip_bfloat16* __restrict__ out,
    int K, int N, size_t sInC, size_t sOutC)
{
    __shared__ float tile[32][33];
    const float* ip = in + blockIdx.z * sInC;
    __hip_bfloat16* op = out + blockIdx.z * sOutC;
    const int n0 = blockIdx.x * 32, k0 = blockIdx.y * 32;
    const int x = threadIdx.x, y = threadIdx.y;
    #pragma unroll
    for (int j = 0; j < 4; ++j)
        tile[y + 8 * j][x] = ip[(size_t)(k0 + y + 8 * j) * N + n0 + x];
    __syncthreads();
    #pragma unroll
    for (int j = 0; j < 4; ++j)
        op[(size_t)(n0 + y + 8 * j) * K + k0 + x] = __float2bfloat16(tile[x][y + 8 * j]);
}

struct CvtJobs {
    const float* in[8];
    __hip_bfloat16* out[8];
    int N[8], K[8], ntn[8], npc[8], end[8];
};

// proj+sparsemax row body (one wave per row), shared by both paths
__device__ __forceinline__ void proj_row(
    const float* __restrict__ x, const float* __restrict__ Wp,
    const float* __restrict__ bp, float* __restrict__ p,
    __hip_bfloat16* __restrict__ xbf, int gw, int lane, int D)
{
    const float* xr = x + (size_t)gw * D;
    __hip_bfloat16* xo = xbf + (size_t)gw * D;
    float acc[8] = {0.f, 0.f, 0.f, 0.f, 0.f, 0.f, 0.f, 0.f};
    for (int d = lane; d < D; d += 64) {
        float xv = xr[d];
        xo[d] = __float2bfloat16(xv);
        #pragma unroll
        for (int c = 0; c < 8; ++c) acc[c] = fmaf(xv, Wp[d * 8 + c], acc[c]);
    }
    #pragma unroll
    for (int off = 32; off > 0; off >>= 1) {
        #pragma unroll
        for (int c = 0; c < 8; ++c) acc[c] += __shfl_xor(acc[c], off, 64);
    }
    if (lane == 0) {
        float s[8], zs[8];
        #pragma unroll
        for (int c = 0; c < 8; ++c) { s[c] = acc[c] + bp[c]; zs[c] = s[c]; }
        for (int i = 1; i < 8; ++i) {
            float v = zs[i];
            int j = i - 1;
            while (j >= 0 && zs[j] < v) { zs[j + 1] = zs[j]; --j; }
            zs[j + 1] = v;
        }
        float cs = 0.f, csel = 1.f;
        int kz = 1;
        for (int k = 1; k <= 8; ++k) {
            cs += zs[k - 1];
            if (1.f + (float)k * zs[k - 1] > cs) { kz = k; csel = cs; }
        }
        float tau = (csel - 1.f) / (float)kz;
        #pragma unroll
        for (int c = 0; c < 8; ++c) p[gw * 8 + c] = fmaxf(s[c] - tau, 0.f);
    }
}

// ONE launch: blocks 0..1023 do proj+sparsemax+x->bf16; the rest convert+
// transpose all 8 weight layers. proj latency hides under cvt's memory BW.
__global__ __launch_bounds__(256) void front_pass(
    CvtJobs j, const float* __restrict__ x, const float* __restrict__ Wp,
    const float* __restrict__ bp, float* __restrict__ p,
    __hip_bfloat16* __restrict__ xbf)
{
    int bid = blockIdx.x;
    const int t = threadIdx.x;
    if (bid < 1024) {
        proj_row(x, Wp, bp, p, xbf, bid * 4 + (t >> 6), t & 63, 512);
        return;
    }
    bid -= 1024;
    __shared__ float tile[32][33];
    int l = 0;
    while (bid >= j.end[l]) ++l;
    const int start = l ? j.end[l - 1] : 0;
    const int local = bid - start;
    const int chart = local / j.npc[l];
    const int rem = local - chart * j.npc[l];
    const int K = j.K[l], N = j.N[l];
    const int n0 = (rem % j.ntn[l]) * 32;
    const int k0 = (rem / j.ntn[l]) * 32;
    const float* ip = j.in[l] + (size_t)chart * K * N;
    __hip_bfloat16* op = j.out[l] + (size_t)chart * K * N;
    const int xx = t & 31, yy = t >> 5;
    #pragma unroll
    for (int jj = 0; jj < 4; ++jj)
        tile[yy + 8 * jj][xx] = ip[(size_t)(k0 + yy + 8 * jj) * N + n0 + xx];
    __syncthreads();
    #pragma unroll
    for (int jj = 0; jj < 4; ++jj)
        op[(size_t)(n0 + yy + 8 * jj) * K + k0 + xx] =
            __float2bfloat16(tile[xx][yy + 8 * jj]);
}

// recon_x + recon_errors + ALL losses + finalize in one launch (G=8 path).
__global__ __launch_bounds__(256) void recon_losses(
    const float* __restrict__ x, const __hip_bfloat16* __restrict__ xrec,
    const float* __restrict__ p, float* __restrict__ recon_x,
    float* __restrict__ acc, float* __restrict__ scal, int nblocks)
{
    __shared__ float s[11];
    const int t = threadIdx.x;
    if (t < 11) s[t] = 0.f;
    __syncthreads();

    const int wid = t >> 6, lane = t & 63;
    const size_t b = (size_t)blockIdx.x * 4 + wid;
    const float4* xp = (const float4*)(x + b * 512);
    const float4 x0 = xp[lane * 2], x1 = xp[lane * 2 + 1];
    const float xv[8] = {x0.x, x0.y, x0.z, x0.w, x1.x, x1.y, x1.z, x1.w};
    float r[8] = {0.f, 0.f, 0.f, 0.f, 0.f, 0.f, 0.f, 0.f};
    float er[8], pr[8];

    #pragma unroll
    for (int cc = 0; cc < 8; ++cc) {
        const ushort_t* xr =
            (const ushort_t*)xrec + ((size_t)cc * 4096 + b) * 512 + lane * 8;
        bf16x8 v = *(const bf16x8*)xr;
        float pv = p[b * 8 + cc];
        pr[cc] = pv;
        float e = 0.f;
        #pragma unroll
        for (int jj = 0; jj < 8; ++jj) {
            float f = (float)v[jj];
            r[jj] = fmaf(pv, f, r[jj]);
            float d = xv[jj] - f;
            e = fmaf(d, d, e);
        }
        #pragma unroll
        for (int off = 1; off < 64; off <<= 1) e += __shfl_xor(e, off, 64);
        er[cc] = e;
    }

    float4* op = (float4*)(recon_x + b * 512);
    op[lane * 2]     = (float4){r[0], r[1], r[2], r[3]};
    op[lane * 2 + 1] = (float4){r[4], r[5], r[6], r[7]};

    float sm = 0.f;
    #pragma unroll
    for (int jj = 0; jj < 8; ++jj) {
        float d = r[jj] - xv[jj];
        sm = fmaf(d, d, sm);
    }
    #pragma unroll
    for (int off = 1; off < 64; off <<= 1) sm += __shfl_xor(sm, off, 64);
    if (lane == 0) atomicAdd(&s[10], sm);

    if (lane == 0) {
        float mn = er[0];
        #pragma unroll
        for (int c = 1; c < 8; ++c) mn = fminf(mn, er[c]);
        float qv[8], se = 0.f;
        #pragma unroll
        for (int c = 0; c < 8; ++c) { qv[c] = expf(mn - er[c]); se += qv[c]; }
        float rl = 0.f, tl = 0.f;
        #pragma unroll
        for (int c = 0; c < 8; ++c) {
            rl = fmaf(pr[c], er[c], rl);
            tl = fmaf(qv[c] / se, logf(pr[c] + 1e-8f), tl);
        }
        atomicAdd(&s[0], rl);
        atomicAdd(&s[1], tl);
        #pragma unroll
        for (int c = 0; c < 8; ++c) atomicAdd(&s[2 + c], pr[c]);
    }
    __syncthreads();

    if (t < 11) {
        atomicAdd(&acc[t], s[t]);
        __threadfence();
    }
    __syncthreads();

    if (t == 0) {
        unsigned tk = atomicAdd((unsigned*)&acc[12], 1u);
        if (tk == (unsigned)(nblocks - 1)) {
            volatile float* va = acc;
            const float invB = 1.f / 4096.f;
            float recon = va[0] * invB;
            float trans = -va[1] * invB;
            float nondom = 0.f;
            for (int c = 0; c < 8; ++c) {
                float mp = va[2 + c] * invB;
                float d = mp - 0.125f;
                nondom = fmaf(d, d, nondom);
            }
            float mse = va[10] / (4096.f * 512.f);
            scal[0] = recon + trans + nondom;
            scal[1] = recon;
            scal[2] = nondom;
            scal[3] = trans;
            scal[4] = mse;
        }
    }
}

// fallback kernels (small-ws path) -------------------------------------------
__global__ __launch_bounds__(256) void recon_group(
    const float* __restrict__ x, const __hip_bfloat16* __restrict__ xrec,
    const float* __restrict__ p, float* __restrict__ recon_x,
    float* __restrict__ err, int c0, int G)
{
    const int wid = threadIdx.x >> 6, lane = threadIdx.x & 63;
    const size_t b = (size_t)blockIdx.x * 4 + wid;
    const float4* xp = (const float4*)(x + b * 512);
    const float4 x0 = xp[lane * 2], x1 = xp[lane * 2 + 1];
    const float xv[8] = {x0.x, x0.y, x0.z, x0.w, x1.x, x1.y, x1.z, x1.w};
    float r[8] = {0.f, 0.f, 0.f, 0.f, 0.f, 0.f, 0.f, 0.f};

    for (int cc = 0; cc < G; ++cc) {
        const ushort_t* xr =
            (const ushort_t*)xrec + ((size_t)cc * 4096 + b) * 512 + lane * 8;
        bf16x8 v = *(const bf16x8*)xr;
        float pv = p[b * 8 + c0 + cc];
        float e = 0.f;
        #pragma unroll
        for (int jj = 0; jj < 8; ++jj) {
            float f = (float)v[jj];
            r[jj] = fmaf(pv, f, r[jj]);
            float d = xv[jj] - f;
            e = fmaf(d, d, e);
        }
        #pragma unroll
        for (int off = 1; off < 64; off <<= 1) e += __shfl_xor(e, off, 64);
        if (lane == 0) err[b * 8 + c0 + cc] = e;
    }

    float4* op = (float4*)(recon_x + b * 512);
    float4 o0 = {r[0], r[1], r[2], r[3]}, o1 = {r[4], r[5], r[6], r[7]};
    if (c0) {
        float4 t0 = op[lane * 2], t1 = op[lane * 2 + 1];
        o0.x += t0.x; o0.y += t0.y; o0.z += t0.z; o0.w += t0.w;
        o1.x += t1.x; o1.y += t1.y; o1.z += t1.z; o1.w += t1.w;
    }
    op[lane * 2] = o0;
    op[lane * 2 + 1] = o1;
}

__global__ __launch_bounds__(256) void tail_reduce(
    const float* __restrict__ p, const float* __restrict__ err,
    const float* __restrict__ recon_x, const float* __restrict__ x,
    float* __restrict__ acc, float* __restrict__ scal,
    int B, int D, int nblocks)
{
    __shared__ float s[11];
    const int t = threadIdx.x;
    if (t < 11) s[t] = 0.f;
    __syncthreads();
    int b = blockIdx.x * 256 + t;
    if (b < B) {
        float pr[8], er[8];
        #pragma unroll
        for (int c = 0; c < 8; ++c) { pr[c] = p[b * 8 + c]; er[c] = err[b * 8 + c]; }
        float mn = er[0];
        #pragma unroll
        for (int c = 1; c < 8; ++c) mn = fminf(mn, er[c]);
        float q[8], se = 0.f;
        #pragma unroll
        for (int c = 0; c < 8; ++c) { q[c] = expf(mn - er[c]); se += q[c]; }
        float rl = 0.f, tl = 0.f;
        #pragma unroll
        for (int c = 0; c < 8; ++c) {
            rl = fmaf(pr[c], er[c], rl);
            tl = fmaf(q[c] / se, logf(pr[c] + 1e-8f), tl);
        }
        atomicAdd(&s[0], rl);
        atomicAdd(&s[1], tl);
        #pragma unroll
        for (int c = 0; c < 8; ++c) atomicAdd(&s[2 + c], pr[c]);
    }
    float sm = 0.f;
    const int n = B * D;
    for (int i = blockIdx.x * 256 + t; i < n; i += nblocks * 256) {
        float d = recon_x[i] - x[i];
        sm = fmaf(d, d, sm);
    }
    atomicAdd(&s[10], sm);
    __syncthreads();
    if (t < 11) { atomicAdd(&acc[t], s[t]); __threadfence(); }
    __syncthreads();
    if (t == 0) {
        unsigned tk = atomicAdd((unsigned*)&acc[12], 1u);
        if (tk == (unsigned)(nblocks - 1)) {
            volatile float* va = acc;
            float invB = 1.f / (float)B;
            float recon = va[0] * invB;
            float trans = -va[1] * invB;
            float nondom = 0.f;
            for (int c = 0; c < 8; ++c) {
                float mp = va[2 + c] * invB;
                float d = mp - 0.125f;
                nondom = fmaf(d, d, nondom);
            }
            float mse = va[10] / ((float)B * (float)D);
            scal[0] = recon + trans + nondom;
            scal[1] = recon;
            scal[2] = nondom;
            scal[3] = trans;
            scal[4] = mse;
        }
    }
}

__global__ __launch_bounds__(256) void proj_sparsemax(
    const float* __restrict__ x, const float* __restrict__ Wp,
    const float* __restrict__ bp, float* __restrict__ p,
    __hip_bfloat16* __restrict__ xbf, int B, int D)
{
    int gw = (blockIdx.x * blockDim.x + threadIdx.x) >> 6;
    if (gw >= B) return;
    proj_row(x, Wp, bp, p, xbf, gw, threadIdx.x & 63, D);
}
// ----------------------------------------------------------------------------

extern "C" void kernel_launch(void* const* d_in, const int* in_sizes, int n_in,
                              void* d_out, int out_size, void* d_ws, size_t ws_size,
                              hipStream_t stream)
{
    const int B = 4096, D = 512, L = 64, H = 1024, C = 8;

    const float* x   = (const float*)d_in[0];
    const float* We1 = (const float*)d_in[1];
    const float* be1 = (const float*)d_in[2];
    const float* We2 = (const float*)d_in[3];
    const float* be2 = (const float*)d_in[4];
    const float* We3 = (const float*)d_in[5];
    const float* be3 = (const float*)d_in[6];
    const float* We4 = (const float*)d_in[7];
    const float* be4 = (const float*)d_in[8];
    const float* Wd1 = (const float*)d_in[9];
    const float* bd1 = (const float*)d_in[10];
    const float* Wd2 = (const float*)d_in[11];
    const float* bd2 = (const float*)d_in[12];
    const float* Wd3 = (const float*)d_in[13];
    const float* bd3 = (const float*)d_in[14];
    const float* Wd4 = (const float*)d_in[15];
    const float* bd4 = (const float*)d_in[16];
    const float* Wp  = (const float*)d_in[17];
    const float* bp  = (const float*)d_in[18];

    float* out     = (float*)d_out;
    float* recon_x = out;                          // [B,D]
    float* zfp     = out + (size_t)B * D;          // [B,C,L]
    float* p       = zfp + (size_t)B * C * L;      // [B,C]
    float* scal    = p + (size_t)B * C;            // 5 scalars

    const dim3 cb(32, 8);
    const dim3 gSH(32, 4, 8);   // 128x256 tiles, N=1024
    const dim3 gSD(32, 2, 8);   // N=512

    // --- big-workspace path: all weights converted once, fused front/tail ---
    const size_t eHD = (size_t)C * H * D;
    const size_t eHH = (size_t)C * H * H;
    const size_t eHL = (size_t)C * H * L;
    const size_t bigNeed = ((size_t)B * D + (size_t)C * B * L +
                            2 * eHD + 4 * eHH + 2 * eHL +
                            2ull * C * B * H + (size_t)C * B * D) * 2ull + 4096;

    if (ws_size >= bigNeed) {
        char* w = (char*)d_ws;
        __hip_bfloat16* xbf  = (__hip_bfloat16*)w; w += (size_t)B * D * 2;
        __hip_bfloat16* zbf  = (__hip_bfloat16*)w; w += (size_t)C * B * L * 2;
        __hip_bfloat16* wE1  = (__hip_bfloat16*)w; w += eHD * 2;
        __hip_bfloat16* wE2  = (__hip_bfloat16*)w; w += eHH * 2;
        __hip_bfloat16* wE3  = (__hip_bfloat16*)w; w += eHH * 2;
        __hip_bfloat16* wE4  = (__hip_bfloat16*)w; w += eHL * 2;
        __hip_bfloat16* wD1  = (__hip_bfloat16*)w; w += eHL * 2;
        __hip_bfloat16* wD2  = (__hip_bfloat16*)w; w += eHH * 2;
        __hip_bfloat16* wD3  = (__hip_bfloat16*)w; w += eHH * 2;
        __hip_bfloat16* wD4  = (__hip_bfloat16*)w; w += eHD * 2;
        __hip_bfloat16* hA   = (__hip_bfloat16*)w; w += (size_t)C * B * H * 2;
        __hip_bfloat16* hB   = (__hip_bfloat16*)w; w += (size_t)C * B * H * 2;
        __hip_bfloat16* xrec = (__hip_bfloat16*)w; w += (size_t)C * B * D * 2;
        float* acc = (float*)w;

        hipMemsetAsync(acc, 0, 16 * sizeof(float), stream);

        CvtJobs j;
        const float* ins[8]  = {We1, We2, We3, We4, Wd1, Wd2, Wd3, Wd4};
        __hip_bfloat16* outs[8] = {wE1, wE2, wE3, wE4, wD1, wD2, wD3, wD4};
        int Ks[8] = {D, H, H, H, L, H, H, H};
        int Ns[8] = {H, H, H, L, H, H, H, D};
        int total = 0;
        for (int l = 0; l < 8; ++l) {
            j.in[l] = ins[l]; j.out[l] = outs[l];
            j.K[l] = Ks[l]; j.N[l] = Ns[l];
            j.ntn[l] = Ns[l] / 32;
            j.npc[l] = (Ns[l] / 32) * (Ks[l] / 32);
            total += j.npc[l] * 8;
            j.end[l] = total;
        }
        // ONE launch: proj+sparsemax (1024 blocks) ∥ weight cvt (total blocks)
        front_pass<<<1024 + total, 256, 0, stream>>>(j, x, Wp, bp, p, xbf);

        gemmS<0, 16, 2><<<gSH, 512, 0, stream>>>(
            xbf, 0, D, wE1, (size_t)H * D, be1, H, hA, (size_t)B * H, H);
        gemmS<0, 32, 2><<<gSH, 512, 0, stream>>>(
            hA, (size_t)B * H, H, wE2, (size_t)H * H, be2, H, hB, (size_t)B * H, H);
        gemmS<0, 32, 2><<<gSH, 512, 0, stream>>>(
            hB, (size_t)B * H, H, wE3, (size_t)H * H, be3, H, hA, (size_t)B * H, H);
        mfma_gemm<64, 1><<<dim3(32, 1, 8), 256, 0, stream>>>(
            hA, (size_t)B * H, H, H, wE4, (size_t)L * H, be4, L,
            zbf, (size_t)B * L, L, zfp, 0);
        gemmS<0, 2, 2><<<gSH, 512, 0, stream>>>(
            zbf, (size_t)B * L, L, wD1, (size_t)H * L, bd1, H, hB, (size_t)B * H, H);
        gemmS<0, 32, 2><<<gSH, 512, 0, stream>>>(
            hB, (size_t)B * H, H, wD2, (size_t)H * H, bd2, H, hA, (size_t)B * H, H);
        gemmS<0, 32, 2><<<gSH, 512, 0, stream>>>(
            hA, (size_t)B * H, H, wD3, (size_t)H * H, bd3, H, hB, (size_t)B * H, H);
        gemmS<2, 32, 1><<<gSD, 512, 0, stream>>>(
            hB, (size_t)B * H, H, wD4, (size_t)D * H, bd4, D, xrec, (size_t)B * D, D);

        recon_losses<<<B / 4, 256, 0, stream>>>(x, xrec, p, recon_x, acc, scal, B / 4);
        return;
    }

    // --- fallback: per-layer cvtT, grouped charts ---
    const size_t perG = ((size_t)H * H + 2ull * B * H + (size_t)B * D) * 2ull;
    const size_t fixedB = ((size_t)B * D + (size_t)C * B * L) * 2ull +
                          ((size_t)B * C + 16) * 4ull + 1024;
    int G = 8;
    while (G > 1 && fixedB + perG * (size_t)G > ws_size) G >>= 1;

    char* w = (char*)d_ws;
    __hip_bfloat16* xbf  = (__hip_bfloat16*)w; w += (size_t)B * D * 2;
    __hip_bfloat16* zbf  = (__hip_bfloat16*)w; w += (size_t)C * B * L * 2;
    __hip_bfloat16* wbuf = (__hip_bfloat16*)w; w += (size_t)G * H * H * 2;
    __hip_bfloat16* hA   = (__hip_bfloat16*)w; w += (size_t)G * B * H * 2;
    __hip_bfloat16* hB   = (__hip_bfloat16*)w; w += (size_t)G * B * H * 2;
    __hip_bfloat16* xrec = (__hip_bfloat16*)w; w += (size_t)G * B * D * 2;
    float* err = (float*)w; w += (size_t)B * C * 4;
    float* acc = (float*)w;

    hipMemsetAsync(acc, 0, 16 * sizeof(float), stream);
    proj_sparsemax<<<B / 4, 256, 0, stream>>>(x, Wp, bp, p, xbf, B, D);

    for (int c0 = 0; c0 < C; c0 += G) {
        cvtT<<<dim3(H / 32, D / 32, G), cb, 0, stream>>>(
            We1 + (size_t)c0 * D * H, wbuf, D, H, (size_t)D * H, (size_t)D * H);
        gemmS<0, 16, 2><<<gSH, 512, 0, stream>>>(
            xbf, 0, D, wbuf, (size_t)D * H, be1 + (size_t)c0 * H, H,
            hA, (size_t)B * H, H);
        cvtT<<<dim3(H / 32, H / 32, G), cb, 0, stream>>>(
            We2 + (size_t)c0 * H * H, wbuf, H, H, (size_t)H * H, (size_t)H * H);
        gemmS<0, 32, 2><<<gSH, 512, 0, stream>>>(
            hA, (size_t)B * H, H, wbuf, (size_t)H * H, be2 + (size_t)c0 * H, H,
            hB, (size_t)B * H, H);
        cvtT<<<dim3(H / 32, H / 32, G), cb, 0, stream>>>(
            We3 + (size_t)c0 * H * H, wbuf, H, H, (size_t)H * H, (size_t)H * H);
        gemmS<0, 32, 2><<<gSH, 512, 0, stream>>>(
            hB, (size_t)B * H, H, wbuf, (size_t)H * H, be3 + (size_t)c0 * H, H,
            hA, (size_t)B * H, H);
        cvtT<<<dim3(L / 32, H / 32, G), cb, 0, stream>>>(
            We4 + (size_t)c0 * H * L, wbuf, H, L, (size_t)H * L, (size_t)H * L);
        mfma_gemm<64, 1><<<dim3(32, 1, G), 256, 0, stream>>>(
            hA, (size_t)B * H, H, H, wbuf, (size_t)H * L, be4 + (size_t)c0 * L, L,
            zbf + (size_t)c0 * B * L, (size_t)B * L, L, zfp, c0);
        cvtT<<<dim3(H / 32, L / 32, G), cb, 0, stream>>>(
            Wd1 + (size_t)c0 * L * H, wbuf, L, H, (size_t)L * H, (size_t)L * H);
        gemmS<0, 2, 2><<<gSH, 512, 0, stream>>>(
            zbf + (size_t)c0 * B * L, (size_t)B * L, L, wbuf, (size_t)L * H,
            bd1 + (size_t)c0 * H, H, hB, (size_t)B * H, H);
        cvtT<<<dim3(H / 32, H / 32, G), cb, 0, stream>>>(
            Wd2 + (size_t)c0 * H * H, wbuf, H, H, (size_t)H * H, (size_t)H * H);
        gemmS<0, 32, 2><<<gSH, 512, 0, stream>>>(
            hB, (size_t)B * H, H, wbuf, (size_t)H * H, bd2 + (size_t)c0 * H, H,
            hA, (size_t)B * H, H);
        cvtT<<<dim3(H / 32, H / 32, G), cb, 0, stream>>>(
            Wd3 + (size_t)c0 * H * H, wbuf, H, H, (size_t)H * H, (size_t)H * H);
        gemmS<0, 32, 2><<<gSH, 512, 0, stream>>>(
            hA, (size_t)B * H, H, wbuf, (size_t)H * H, bd3 + (size_t)c0 * H, H,
            hB, (size_t)B * H, H);
        cvtT<<<dim3(D / 32, H / 32, G), cb, 0, stream>>>(
            Wd4 + (size_t)c0 * H * D, wbuf, H, D, (size_t)H * D, (size_t)H * D);
        gemmS<2, 32, 1><<<gSD, 512, 0, stream>>>(
            hB, (size_t)B * H, H, wbuf, (size_t)H * D, bd4 + (size_t)c0 * D, D,
            xrec, (size_t)B * D, D);
        recon_group<<<B / 4, 256, 0, stream>>>(x, xrec, p, recon_x, err, c0, G);
    }

    tail_reduce<<<1024, 256, 0, stream>>>(p, err, recon_x, x, acc, scal, B, D, 1024);
}